// Round 11
// baseline (911.967 us; speedup 1.0000x reference)
//
#include <hip/hip_runtime.h>

#define NPTS 60000
#define C 128
#define K 32
#define FF 512
#define CO 128
#define H 8
#define DH 16
#define EPS 1e-5f

// ---- fp32 weight layout (float elements) ----
constexpr int OFF_INPROJ_W = 0;          // 384*128
constexpr int OFF_INPROJ_B = 49152;      // 384
constexpr int OFF_OUT_W    = 49536;      // 16384
constexpr int OFF_OUT_B    = 65920;      // 128
constexpr int OFF_QPOS_W   = 66048;      // 384
constexpr int OFF_QPOS_B   = 66432;      // 128
constexpr int OFF_KPOS_W   = 66560;      // 384
constexpr int OFF_KPOS_B   = 66944;      // 128
constexpr int OFF_N1G      = 67072;
constexpr int OFF_N1B      = 67200;
constexpr int OFF_N2G      = 67328;
constexpr int OFF_N2B      = 67456;
constexpr int OFF_LIN1_W   = 67584;      // 65536
constexpr int OFF_LIN1_B   = 133120;     // 512
constexpr int OFF_LIN2_W   = 133632;     // 65536
constexpr int OFF_LIN2_B   = 199168;     // 128
constexpr int OFF_OUTL_W   = 199296;     // 16384
constexpr int OFF_OUTL_B   = 215680;     // 128
constexpr int OFF_BOG      = 215808;
constexpr int OFF_BOB      = 215936;
constexpr int WTOTAL       = 216064;

// ---- bf16 weight copies (ushort elements within wsB) ----
constexpr int B_INPROJ = 0;        // 384x128 rows: wq(0..127) wk(128..255) wv(256..383)
constexpr int B_OUTW   = 49152;    // 128x128
constexpr int B_LIN1   = 65536;    // 512x128
constexpr int B_LIN2   = 131072;   // 128x512
constexpr int B_OUTL   = 196608;   // 128x128
constexpr int B_WKT    = 212992;   // 128x128: wkT[c][r] = wk[r][c]
constexpr int B_KPW4   = 229376;   // 128 x float4 {w0,w1,w2,b} (fp32, 2048 B)
constexpr size_t OFF_WB_BYTES  = 1587456;
constexpr size_t OFF_BIG_BYTES = 2048256;
constexpr size_t QK_BYTES = (size_t)NPTS * 1024 * 2;   // qkt[n][h*128+c] bf16

typedef __attribute__((ext_vector_type(8))) short bfrag8;
typedef __attribute__((ext_vector_type(4))) float f32x4;

__device__ __forceinline__ float bf2f(unsigned short s) {
    return __uint_as_float(((unsigned)s) << 16);
}
__device__ __forceinline__ unsigned short f2bf(float f) {
    unsigned u = __float_as_uint(f);
    u += 0x7fffu + ((u >> 16) & 1u);
    return (unsigned short)(u >> 16);
}
__device__ __forceinline__ float ldE(const float* p, long i) { return p[i]; }
__device__ __forceinline__ float ldE(const unsigned short* p, long i) { return bf2f(p[i]); }
__device__ __forceinline__ void stE(float* p, long i, float v) { p[i] = v; }
__device__ __forceinline__ void stE(unsigned short* p, long i, float v) { p[i] = f2bf(v); }
__device__ __forceinline__ float ldF(const void* p, long i, int bf) {
    return bf ? bf2f(((const unsigned short*)p)[i]) : ((const float*)p)[i];
}
__device__ __forceinline__ bfrag8 ldfrag(const unsigned short* base, int stride, int lane, int k0) {
    return *(const bfrag8*)(base + (lane & 15) * stride + k0 + ((lane >> 4) << 3));
}

// ---- dtype probe ----
__global__ __launch_bounds__(256) void k_detect(const unsigned short* __restrict__ f,
                                                int* __restrict__ flag) {
    __shared__ int cnt_s;
    if (threadIdx.x == 0) cnt_s = 0;
    __syncthreads();
    int sane = 0;
    for (int j = 0; j < 16; ++j) {
        unsigned short u = f[threadIdx.x * 16 + j];
        int e = (u >> 7) & 255;
        sane += (u == 0 || (e >= 100 && e <= 142)) ? 1 : 0;
    }
    atomicAdd(&cnt_s, sane);
    __syncthreads();
    if (threadIdx.x == 0) *flag = (cnt_s >= 3686) ? 1 : 0;
}

struct WTab {
    const void* src[20];
    int beg[20];
    int end[20];
    int bo[20];
};

__global__ __launch_bounds__(256) void k_cvt_weights(WTab tab, float* __restrict__ ws,
                                                     unsigned short* __restrict__ wsB,
                                                     const int* __restrict__ flagp) {
    int bf = *flagp;
    int gid = blockIdx.x * 256 + threadIdx.x;
    #pragma unroll
    for (int j = 0; j < 20; ++j) {
        if (gid >= tab.beg[j] && gid < tab.end[j]) {
            int off = gid - tab.beg[j];
            float v;
            unsigned short raw;
            if (bf) { raw = ((const unsigned short*)tab.src[j])[off]; v = bf2f(raw); }
            else    { v = ((const float*)tab.src[j])[off]; raw = f2bf(v); }
            ws[gid] = v;
            if (tab.bo[j] >= 0) wsB[tab.bo[j] + off] = raw;
            if (j == 0 && off >= 16384 && off < 32768) {   // wk rows -> transposed copy
                int r = (off >> 7) - 128;
                int c = off & 127;
                wsB[B_WKT + c * C + r] = raw;
            }
            if (j == 6) {  // kpos_w -> packed float4 {w0,w1,w2,b}
                int c = off / 3, comp = off - 3 * c;
                ((float*)(wsB + B_KPW4))[c * 4 + comp] = v;
            }
            if (j == 7) {  // kpos_b
                ((float*)(wsB + B_KPW4))[off * 4 + 3] = v;
            }
        }
    }
}

// ---- fused coords + qpos + Q projection + per-head qkt precompute ----
// qkt tiles stored straight from D-regs to Qk (u16, fire-and-forget) -> zero syncs
// in the head loop; LDS 18 KB, 3 syncs total.
__global__ __launch_bounds__(256) void k_proj(
    const float* __restrict__ wsW, const unsigned short* __restrict__ wsB,
    const void* __restrict__ featv, const int* __restrict__ flagp,
    const int* __restrict__ indices, float* __restrict__ coords,
    unsigned short* __restrict__ Qk)
{
    __shared__ __align__(16) unsigned short sqb[32][136];
    __shared__ __align__(16) unsigned short sqh[32][136];
    __shared__ float scd[32][4];
    int t = threadIdx.x;
    int row0 = blockIdx.x * 32;
    const int bf = *flagp;
    if (t < 96) {
        int r = t / 3, j = t - 3 * r;
        int n = row0 + r;
        int srci = (j == 0) ? 3 : (j == 1 ? 2 : 1);
        float vs = (j == 2) ? 0.2f : 0.1f;
        float mn = (j == 2) ? -3.0f : -40.0f;
        float v = ((float)indices[n * 4 + srci] + 0.5f) * vs + mn;
        scd[r][j] = v;
        coords[n * 3 + j] = v;
    }
    __syncthreads();
    const float* qpw = wsW + OFF_QPOS_W;
    const float* qpb = wsW + OFF_QPOS_B;
    for (int i = t; i < 32 * C; i += 256) {
        int r = i >> 7, c = i & 127;
        float x = ldF(featv, (long)row0 * C + i, bf);
        float a = qpb[c] + scd[r][0]*qpw[c*3] + scd[r][1]*qpw[c*3+1] + scd[r][2]*qpw[c*3+2];
        sqb[r][c] = f2bf(x + fmaxf(a, 0.0f));
    }
    __syncthreads();
    int lane = t & 63, w = t >> 6;
    int col = lane & 15, quad = lane >> 4;
    // Q-GEMM: qh = q @ wq^T + bq  -> sqh (bf16, LDS only)
    for (int tid = w; tid < 16; tid += 4) {
        int mt = tid & 1, nt = tid >> 1, n0 = nt * 16;
        f32x4 acc = {0.f, 0.f, 0.f, 0.f};
        const unsigned short* aB = &sqb[mt*16][0];
        const unsigned short* bB = wsB + B_INPROJ + n0 * C;
        #pragma unroll
        for (int kt = 0; kt < 4; ++kt) {
            bfrag8 a = ldfrag(aB, 136, lane, kt*32);
            bfrag8 b = ldfrag(bB, C, lane, kt*32);
            acc = __builtin_amdgcn_mfma_f32_16x16x32_bf16(a, b, acc, 0, 0, 0);
        }
        #pragma unroll
        for (int r = 0; r < 4; ++r) {
            int n = n0 + col;
            sqh[mt*16 + quad*4 + r][n] = f2bf(acc[r] + wsW[OFF_INPROJ_B + n]);
        }
    }
    __syncthreads();
    // per-head qkt: A = sqh cols [h*16,h*16+16), B = wkT (K=16 zero-padded),
    // D stored DIRECTLY to Qk (no LDS round-trip, no syncs)
    const unsigned short* wkT = wsB + B_WKT;
    bfrag8 zf = {0,0,0,0,0,0,0,0};
    for (int h = 0; h < 8; ++h) {
        for (int tid = w; tid < 16; tid += 4) {
            int mt = tid & 1, nt = tid >> 1, n0 = nt * 16;
            bfrag8 a = zf, b = zf;
            if (quad < 2) {
                a = *(const bfrag8*)(&sqh[mt*16 + col][h*16 + quad*8]);
                b = *(const bfrag8*)(wkT + (n0 + col) * C + h*16 + quad*8);
            }
            f32x4 acc = {0.f, 0.f, 0.f, 0.f};
            acc = __builtin_amdgcn_mfma_f32_16x16x32_bf16(a, b, acc, 0, 0, 0);
            #pragma unroll
            for (int r = 0; r < 4; ++r) {
                long pt = row0 + mt*16 + quad*4 + r;
                Qk[pt * 1024 + h * 128 + n0 + col] = f2bf(acc[r]);
            }
        }
    }
}

// ---- attention: ONE wave per block; qkt read coalesced from Qk ----
// score[h][k] = 0.25 * qkt_h . (x_gk + p_k);  att = (sum_k attn (x_gk+p_k)) @ wv^T + bv
template <typename T>
__global__ __launch_bounds__(64) void k_attn(
    const float* __restrict__ wsW, const unsigned short* __restrict__ wsB,
    const float* __restrict__ coords, const int* __restrict__ key_idx,
    const void* __restrict__ featv, const int* __restrict__ flagp,
    const unsigned short* __restrict__ Qk, T* __restrict__ Y)
{
    __shared__ __align__(16) unsigned short P[32][136];
    __shared__ __align__(16) unsigned short QZ[8][136];
    __shared__ __align__(16) float SC[8][36];
    __shared__ __align__(16) float REL[32][4];
    __shared__ __align__(16) int   GS[32];
    __shared__ __align__(16) float ATT[132];

    int l = threadIdx.x;
    int n = blockIdx.x;
    int col = l & 15, quad = l >> 4;
    int c0 = 2 * l;
    const int bf = *flagp;

    const float* kpwp = wsW + OFF_KPOS_W;
    float kw00 = kpwp[c0*3],   kw01 = kpwp[c0*3+1], kw02 = kpwp[c0*3+2];
    float kw10 = kpwp[c0*3+3], kw11 = kpwp[c0*3+4], kw12 = kpwp[c0*3+5];
    float kb0 = wsW[OFF_KPOS_B + c0], kb1 = wsW[OFF_KPOS_B + c0 + 1];
    const unsigned short* wvp = wsB + B_INPROJ + 256 * C;

    // Ph0: GS; prefetch qkt A-fragments (coalesced 2KB row); center
    if (l < 32) GS[l] = key_idx[n * K + l];
    float cenx = coords[n*3+0], ceny = coords[n*3+1], cenz = coords[n*3+2];
    bfrag8 ak[4];
    {
        const unsigned short* qkrow = Qk + (long)n * 1024 + (col & 7) * 128;
        #pragma unroll
        for (int ks = 0; ks < 4; ++ks)
            ak[ks] = *(const bfrag8*)(qkrow + ks * 32 + quad * 8);
    }
    // Ph1: rel coords (GS[l] is own-lane -> no barrier needed)
    if (l < 32) {
        int gc = max(GS[l], 0);
        REL[l][0] = coords[gc*3+0] - cenx;
        REL[l][1] = coords[gc*3+1] - ceny;
        REL[l][2] = coords[gc*3+2] - cenz;
        REL[l][3] = 0.f;
    }
    __syncthreads();

    // Ph2: p_full[k][c] = x[g_k][c] + relu(kpos . rel + b); lane owns c0, c0+1
    if (bf) {
        const unsigned* xb = (const unsigned*)featv;
        #pragma unroll 8
        for (int k = 0; k < K; ++k) {
            int gc = max(GS[k], 0);
            unsigned xv = xb[(long)gc * 64 + l];
            float4 rr = *(const float4*)&REL[k][0];
            float p0 = bf2f((unsigned short)xv)
                     + fmaxf(kb0 + rr.x*kw00 + rr.y*kw01 + rr.z*kw02, 0.f);
            float p1 = bf2f((unsigned short)(xv >> 16))
                     + fmaxf(kb1 + rr.x*kw10 + rr.y*kw11 + rr.z*kw12, 0.f);
            *(unsigned*)&P[k][c0] = (unsigned)f2bf(p0) | ((unsigned)f2bf(p1) << 16);
        }
    } else {
        const float2* xf = (const float2*)featv;
        #pragma unroll 8
        for (int k = 0; k < K; ++k) {
            int gc = max(GS[k], 0);
            float2 xv = xf[(long)gc * 64 + l];
            float4 rr = *(const float4*)&REL[k][0];
            float p0 = xv.x + fmaxf(kb0 + rr.x*kw00 + rr.y*kw01 + rr.z*kw02, 0.f);
            float p1 = xv.y + fmaxf(kb1 + rr.x*kw10 + rr.y*kw11 + rr.z*kw12, 0.f);
            *(unsigned*)&P[k][c0] = (unsigned)f2bf(p0) | ((unsigned)f2bf(p1) << 16);
        }
    }
    __syncthreads();

    // Ph4: scores = qkt . p_full  (A = prefetched ak; D rows 8-15 discarded)
    #pragma unroll
    for (int nt = 0; nt < 2; ++nt) {
        int g = GS[nt * 16 + col];
        f32x4 acc = {0.f, 0.f, 0.f, 0.f};
        #pragma unroll
        for (int ks = 0; ks < 4; ++ks) {
            bfrag8 bp = *(const bfrag8*)(&P[nt * 16 + col][0] + ks * 32 + quad * 8);
            acc = __builtin_amdgcn_mfma_f32_16x16x32_bf16(ak[ks], bp, acc, 0, 0, 0);
        }
        if (quad < 2) {
            #pragma unroll
            for (int r = 0; r < 4; ++r) {
                int h = quad * 4 + r, k = nt * 16 + col;
                SC[h][k] = (g < 0) ? -1e30f : acc[r] * 0.25f;
            }
        }
    }
    __syncthreads();

    // Ph5: softmax per h (8 lanes per h, 4 k each)
    {
        int h = l >> 3, sub = l & 7;
        float v0 = SC[h][sub],      v1 = SC[h][sub + 8];
        float v2 = SC[h][sub + 16], v3 = SC[h][sub + 24];
        float m = fmaxf(fmaxf(v0, v1), fmaxf(v2, v3));
        m = fmaxf(m, __shfl_xor(m, 1));
        m = fmaxf(m, __shfl_xor(m, 2));
        m = fmaxf(m, __shfl_xor(m, 4));
        float e0 = __expf(v0 - m), e1 = __expf(v1 - m), e2 = __expf(v2 - m), e3 = __expf(v3 - m);
        float s = e0 + e1 + e2 + e3;
        s += __shfl_xor(s, 1);
        s += __shfl_xor(s, 2);
        s += __shfl_xor(s, 4);
        float inv = 1.0f / s;
        SC[h][sub]      = e0 * inv;
        SC[h][sub + 8]  = e1 * inv;
        SC[h][sub + 16] = e2 * inv;
        SC[h][sub + 24] = e3 * inv;
    }
    __syncthreads();

    // Ph6: z[h][c'] = sum_k attn[h][k] p_full[k][c']
    {
        union { bfrag8 f; unsigned short u[8]; } at8;
        #pragma unroll
        for (int j = 0; j < 8; ++j)
            at8.u[j] = f2bf(SC[col & 7][quad * 8 + j]);
        #pragma unroll
        for (int nt = 0; nt < 8; ++nt) {
            union { bfrag8 f; unsigned short u[8]; } bt;
            #pragma unroll
            for (int j = 0; j < 8; ++j)
                bt.u[j] = P[quad * 8 + j][nt * 16 + col];
            f32x4 d = {0.f, 0.f, 0.f, 0.f};
            d = __builtin_amdgcn_mfma_f32_16x16x32_bf16(at8.f, bt.f, d, 0, 0, 0);
            if (quad < 2) {
                #pragma unroll
                for (int r = 0; r < 4; ++r)
                    QZ[quad * 4 + r][nt * 16 + col] = f2bf(d[r]);
            }
        }
    }
    __syncthreads();

    // Ph7: a2[h][c] = z_h . wv_c ; keep only h == c>>4 diag blocks
    {
        bfrag8 az[4];
        #pragma unroll
        for (int ks = 0; ks < 4; ++ks)
            az[ks] = *(const bfrag8*)(&QZ[0][0] + (col & 7) * 136 + ks * 32 + quad * 8);
        #pragma unroll
        for (int nt = 0; nt < 8; ++nt) {
            f32x4 acc = {0.f, 0.f, 0.f, 0.f};
            #pragma unroll
            for (int ks = 0; ks < 4; ++ks) {
                bfrag8 b = *(const bfrag8*)(wvp + (nt * 16 + col) * C + ks * 32 + quad * 8);
                acc = __builtin_amdgcn_mfma_f32_16x16x32_bf16(az[ks], b, acc, 0, 0, 0);
            }
            if (quad == (nt >> 2))
                ATT[nt * 16 + col] = acc[nt & 3];
        }
    }
    __syncthreads();

    // Ph8: att[c] = a2[c] + bv[c]
    {
        float a0 = ATT[c0]     + wsW[OFF_INPROJ_B + 256 + c0];
        float a1 = ATT[c0 + 1] + wsW[OFF_INPROJ_B + 256 + c0 + 1];
        stE(Y, (long)n * C + c0, a0);
        stE(Y, (long)n * C + c0 + 1, a1);
    }
}

// ---- out-proj + residual + bn1 stats (MFMA) ----
template <typename T>
__global__ __launch_bounds__(256) void k_outproj(
    const float* __restrict__ wsW, const unsigned short* __restrict__ wsB,
    const void* __restrict__ featv, const int* __restrict__ flagp,
    T* __restrict__ Y, float* __restrict__ acc_s)
{
    __shared__ __align__(16) unsigned short sab[32][136];
    __shared__ float syf[32][132];
    int t = threadIdx.x;
    int row0 = blockIdx.x * 32;
    const int bf = *flagp;
    for (int i = t; i < 32 * C; i += 256)
        sab[i>>7][i&127] = f2bf(ldE(Y, (long)row0 * C + i));
    __syncthreads();
    int lane = t & 63, w = t >> 6;
    int col = lane & 15, quad = lane >> 4;
    for (int tid = w; tid < 16; tid += 4) {
        int mt = tid & 1, nt = tid >> 1, n0 = nt * 16;
        f32x4 acc = {0.f, 0.f, 0.f, 0.f};
        const unsigned short* aB = &sab[mt*16][0];
        const unsigned short* bB = wsB + B_OUTW + n0 * C;
        #pragma unroll
        for (int kt = 0; kt < 4; ++kt) {
            bfrag8 a = ldfrag(aB, 136, lane, kt*32);
            bfrag8 b = ldfrag(bB, C, lane, kt*32);
            acc = __builtin_amdgcn_mfma_f32_16x16x32_bf16(a, b, acc, 0, 0, 0);
        }
        #pragma unroll
        for (int r = 0; r < 4; ++r) {
            int m = mt*16 + quad*4 + r;
            int n = n0 + col;
            syf[m][n] = acc[r] + wsW[OFF_OUT_B + n] + ldF(featv, (long)(row0+m)*C + n, bf);
        }
    }
    __syncthreads();
    for (int i = t; i < 32 * C; i += 256)
        stE(Y, (long)row0 * C + i, syf[i>>7][i&127]);
    {
        int c = t & 127, hh = t >> 7;
        float s = 0.f, sq = 0.f;
        for (int r = hh*16; r < hh*16+16; ++r) { float v = syf[r][c]; s += v; sq += v*v; }
        atomicAdd(&acc_s[c], s);
        atomicAdd(&acc_s[C + c], sq);
    }
}

// ---- bn1 + FFN + residual + bn2 stats (MFMA) ----
template <typename T>
__global__ __launch_bounds__(256) void k_ffn(
    const float* __restrict__ wsW, const unsigned short* __restrict__ wsB,
    T* __restrict__ Y, const float* __restrict__ acc1, float* __restrict__ acc2)
{
    __shared__ __align__(16) unsigned short sxb[32][136];
    __shared__ __align__(16) unsigned short sh[32][520];
    __shared__ float nsc[C], nsh[C];
    float (*syf)[132] = (float(*)[132])sh;
    int t = threadIdx.x;
    int row0 = blockIdx.x * 32;
    if (t < C) {
        float m = acc1[t] * (1.0f/NPTS);
        float v = acc1[C+t] * (1.0f/NPTS) - m*m;
        float rs = rsqrtf(v + EPS);
        float sc = rs * wsW[OFF_N1G + t];
        nsc[t] = sc;
        nsh[t] = wsW[OFF_N1B + t] - m * sc;
    }
    __syncthreads();
    for (int i = t; i < 32 * C; i += 256) {
        int c = i & 127;
        sxb[i>>7][c] = f2bf(ldE(Y, (long)row0 * C + i) * nsc[c] + nsh[c]);
    }
    __syncthreads();
    int lane = t & 63, w = t >> 6;
    int col = lane & 15, quad = lane >> 4;
    for (int tid = w; tid < 64; tid += 4) {
        int mt = tid & 1, nt = tid >> 1, n0 = nt * 16;
        f32x4 acc = {0.f, 0.f, 0.f, 0.f};
        const unsigned short* aB = &sxb[mt*16][0];
        const unsigned short* bB = wsB + B_LIN1 + n0 * C;
        #pragma unroll
        for (int kt = 0; kt < 4; ++kt) {
            bfrag8 a = ldfrag(aB, 136, lane, kt*32);
            bfrag8 b = ldfrag(bB, C, lane, kt*32);
            acc = __builtin_amdgcn_mfma_f32_16x16x32_bf16(a, b, acc, 0, 0, 0);
        }
        #pragma unroll
        for (int r = 0; r < 4; ++r) {
            int m = mt*16 + quad*4 + r;
            int n = n0 + col;
            sh[m][n] = f2bf(fmaxf(acc[r] + wsW[OFF_LIN1_B + n], 0.f));
        }
    }
    __syncthreads();
    f32x4 accT[4];
    #pragma unroll
    for (int i = 0; i < 4; ++i) {
        int tid = w + 4*i;
        int mt = tid & 1, nt = tid >> 1, n0 = nt * 16;
        f32x4 acc = {0.f, 0.f, 0.f, 0.f};
        const unsigned short* aB = &sh[mt*16][0];
        const unsigned short* bB = wsB + B_LIN2 + n0 * FF;
        #pragma unroll
        for (int kt = 0; kt < 16; ++kt) {
            bfrag8 a = ldfrag(aB, 520, lane, kt*32);
            bfrag8 b = ldfrag(bB, FF, lane, kt*32);
            acc = __builtin_amdgcn_mfma_f32_16x16x32_bf16(a, b, acc, 0, 0, 0);
        }
        accT[i] = acc;
    }
    __syncthreads();
    #pragma unroll
    for (int i = 0; i < 4; ++i) {
        int tid = w + 4*i;
        int mt = tid & 1, nt = tid >> 1, n0 = nt * 16;
        #pragma unroll
        for (int r = 0; r < 4; ++r) {
            int m = mt*16 + quad*4 + r;
            int n = n0 + col;
            syf[m][n] = accT[i][r] + wsW[OFF_LIN2_B + n] + bf2f(sxb[m][n]);
        }
    }
    __syncthreads();
    for (int i = t; i < 32 * C; i += 256)
        stE(Y, (long)row0 * C + i, syf[i>>7][i&127]);
    {
        int c = t & 127, hh = t >> 7;
        float s = 0.f, sq = 0.f;
        for (int r = hh*16; r < hh*16+16; ++r) { float v = syf[r][c]; s += v; sq += v*v; }
        atomicAdd(&acc2[c], s);
        atomicAdd(&acc2[C + c], sq);
    }
}

// ---- bn2 + output linear + bn3 stats (MFMA) ----
template <typename T>
__global__ __launch_bounds__(256) void k_outl(
    const float* __restrict__ wsW, const unsigned short* __restrict__ wsB,
    T* __restrict__ Y, const float* __restrict__ acc2, float* __restrict__ acc3)
{
    __shared__ __align__(16) unsigned short sxb[32][136];
    __shared__ float syf[32][132];
    __shared__ float nsc[C], nsh[C];
    int t = threadIdx.x;
    int row0 = blockIdx.x * 32;
    if (t < C) {
        float m = acc2[t] * (1.0f/NPTS);
        float v = acc2[C+t] * (1.0f/NPTS) - m*m;
        float rs = rsqrtf(v + EPS);
        float sc = rs * wsW[OFF_N2G + t];
        nsc[t] = sc;
        nsh[t] = wsW[OFF_N2B + t] - m * sc;
    }
    __syncthreads();
    for (int i = t; i < 32 * C; i += 256) {
        int c = i & 127;
        sxb[i>>7][c] = f2bf(ldE(Y, (long)row0 * C + i) * nsc[c] + nsh[c]);
    }
    __syncthreads();
    int lane = t & 63, w = t >> 6;
    int col = lane & 15, quad = lane >> 4;
    for (int tid = w; tid < 16; tid += 4) {
        int mt = tid & 1, nt = tid >> 1, n0 = nt * 16;
        f32x4 acc = {0.f, 0.f, 0.f, 0.f};
        const unsigned short* aB = &sxb[mt*16][0];
        const unsigned short* bB = wsB + B_OUTL + n0 * C;
        #pragma unroll
        for (int kt = 0; kt < 4; ++kt) {
            bfrag8 a = ldfrag(aB, 136, lane, kt*32);
            bfrag8 b = ldfrag(bB, C, lane, kt*32);
            acc = __builtin_amdgcn_mfma_f32_16x16x32_bf16(a, b, acc, 0, 0, 0);
        }
        #pragma unroll
        for (int r = 0; r < 4; ++r) {
            int m = mt*16 + quad*4 + r;
            int n = n0 + col;
            syf[m][n] = acc[r] + wsW[OFF_OUTL_B + n];
        }
    }
    __syncthreads();
    for (int i = t; i < 32 * CO; i += 256)
        stE(Y, (long)row0 * CO + i, syf[i>>7][i&127]);
    {
        int c = t & 127, hh = t >> 7;
        float s = 0.f, sq = 0.f;
        for (int r = hh*16; r < hh*16+16; ++r) { float v = syf[r][c]; s += v; sq += v*v; }
        atomicAdd(&acc3[c], s);
        atomicAdd(&acc3[CO + c], sq);
    }
}

// ---- final BN + relu -> output ----
template <typename T>
__global__ __launch_bounds__(256) void k_final(
    const float* __restrict__ wsW, const T* __restrict__ Y,
    const float* __restrict__ acc3, const int* __restrict__ flagp,
    void* __restrict__ out)
{
    long i = (long)blockIdx.x * 256 + threadIdx.x;
    int c = (int)(i & (CO-1));
    float m = acc3[c] * (1.0f/NPTS);
    float v = acc3[CO+c] * (1.0f/NPTS) - m*m;
    float rs = rsqrtf(v + EPS);
    float y = (ldE(Y, i) - m) * rs * wsW[OFF_BOG + c] + wsW[OFF_BOB + c];
    y = fmaxf(y, 0.f);
    if (*flagp) ((unsigned short*)out)[i] = f2bf(y);
    else        ((float*)out)[i] = y;
}

extern "C" void kernel_launch(void* const* d_in, const int* in_sizes, int n_in,
                              void* d_out, int out_size, void* d_ws, size_t ws_size,
                              hipStream_t stream)
{
    char* base = (char*)d_ws;
    float* wsW = (float*)base;
    float* acc1 = wsW + WTOTAL;
    float* acc2 = acc1 + 256;
    float* acc3 = acc2 + 256;
    int* flagp = (int*)(wsW + WTOTAL + 768);
    float* coords = wsW + WTOTAL + 776;
    unsigned short* wsB = (unsigned short*)(base + OFF_WB_BYTES);

    const void* featv = d_in[0];
    const int* indices = (const int*)d_in[1];
    const int* key_idx = (const int*)d_in[2];

    hipMemsetAsync(acc1, 0, 768 * sizeof(float), stream);
    k_detect<<<1, 256, 0, stream>>>((const unsigned short*)d_in[0], flagp);

    static const int cnt[20] = {49152,384,16384,128,384,128,384,128,128,128,
                                128,128,65536,512,65536,128,16384,128,128,128};
    static const int bofs[20] = {B_INPROJ,-1,B_OUTW,-1,-1,-1,-1,-1,-1,-1,
                                 -1,-1,B_LIN1,-1,B_LIN2,-1,B_OUTL,-1,-1,-1};
    WTab tab;
    int off = 0;
    for (int j = 0; j < 20; ++j) {
        tab.src[j] = d_in[3 + j];
        tab.beg[j] = off;
        tab.end[j] = off + cnt[j];
        tab.bo[j] = bofs[j];
        off += cnt[j];
    }
    k_cvt_weights<<<WTOTAL/256, 256, 0, stream>>>(tab, wsW, wsB, flagp);

    size_t bigN = (size_t)NPTS * C;
    bool f32mode = (ws_size >= OFF_BIG_BYTES + QK_BYTES + bigN * 4);

    unsigned short* Qk = (unsigned short*)(base + OFF_BIG_BYTES);

    k_proj<<<NPTS/32, 256, 0, stream>>>(wsW, wsB, featv, flagp, indices, coords, Qk);

    if (f32mode) {
        float* Y = (float*)(base + OFF_BIG_BYTES + QK_BYTES);
        k_attn<float><<<NPTS, 64, 0, stream>>>(wsW, wsB, coords, key_idx, featv, flagp, Qk, Y);
        k_outproj<float><<<NPTS/32, 256, 0, stream>>>(wsW, wsB, featv, flagp, Y, acc1);
        k_ffn<float><<<NPTS/32, 256, 0, stream>>>(wsW, wsB, Y, acc1, acc2);
        k_outl<float><<<NPTS/32, 256, 0, stream>>>(wsW, wsB, Y, acc2, acc3);
        k_final<float><<<(NPTS*CO)/256, 256, 0, stream>>>(wsW, Y, acc3, flagp, d_out);
    } else {
        unsigned short* Y = (unsigned short*)(base + OFF_BIG_BYTES + QK_BYTES);
        k_attn<unsigned short><<<NPTS, 64, 0, stream>>>(wsW, wsB, coords, key_idx, featv, flagp, Qk, Y);
        k_outproj<unsigned short><<<NPTS/32, 256, 0, stream>>>(wsW, wsB, featv, flagp, Y, acc1);
        k_ffn<unsigned short><<<NPTS/32, 256, 0, stream>>>(wsW, wsB, Y, acc1, acc2);
        k_outl<unsigned short><<<NPTS/32, 256, 0, stream>>>(wsW, wsB, Y, acc2, acc3);
        k_final<unsigned short><<<(NPTS*CO)/256, 256, 0, stream>>>(wsW, Y, acc3, flagp, d_out);
    }
}

// Round 12
// 800.320 us; speedup vs baseline: 1.1395x; 1.1395x over previous
//
#include <hip/hip_runtime.h>

#define NPTS 60000
#define C 128
#define K 32
#define FF 512
#define CO 128
#define H 8
#define DH 16
#define EPS 1e-5f

// ---- fp32 weight layout (float elements) ----
constexpr int OFF_INPROJ_W = 0;          // 384*128
constexpr int OFF_INPROJ_B = 49152;      // 384
constexpr int OFF_OUT_W    = 49536;      // 16384
constexpr int OFF_OUT_B    = 65920;      // 128
constexpr int OFF_QPOS_W   = 66048;      // 384
constexpr int OFF_QPOS_B   = 66432;      // 128
constexpr int OFF_KPOS_W   = 66560;      // 384
constexpr int OFF_KPOS_B   = 66944;      // 128
constexpr int OFF_N1G      = 67072;
constexpr int OFF_N1B      = 67200;
constexpr int OFF_N2G      = 67328;
constexpr int OFF_N2B      = 67456;
constexpr int OFF_LIN1_W   = 67584;      // 65536
constexpr int OFF_LIN1_B   = 133120;     // 512
constexpr int OFF_LIN2_W   = 133632;     // 65536
constexpr int OFF_LIN2_B   = 199168;     // 128
constexpr int OFF_OUTL_W   = 199296;     // 16384
constexpr int OFF_OUTL_B   = 215680;     // 128
constexpr int OFF_BOG      = 215808;
constexpr int OFF_BOB      = 215936;
constexpr int WTOTAL       = 216064;

// ---- bf16 weight copies (ushort elements within wsB) ----
constexpr int B_INPROJ = 0;        // 384x128
constexpr int B_OUTW   = 49152;    // 128x128 (unused by new outproj; kept for layout)
constexpr int B_LIN1   = 65536;    // 512x128
constexpr int B_LIN2   = 131072;   // 128x512
constexpr int B_OUTL   = 196608;   // 128x128
constexpr int B_WKT    = 212992;   // 128x128
constexpr int B_KPW4   = 229376;   // 128 x float4 (fp32, 2048 B)
constexpr int B_M      = 230400;   // 128x1024 bf16 fused (outw ⊗ blockdiag wv)
constexpr int B_OB2    = 361472;   // 128 fp32: out_b + outw@bv
constexpr size_t OFF_WB_BYTES  = 1587456;
constexpr size_t OFF_BIG_BYTES = 2310912;
constexpr size_t QK_BYTES = (size_t)NPTS * 1024 * 2;   // qkt rows; reused as z rows

typedef __attribute__((ext_vector_type(8))) short bfrag8;
typedef __attribute__((ext_vector_type(4))) float f32x4;

__device__ __forceinline__ float bf2f(unsigned short s) {
    return __uint_as_float(((unsigned)s) << 16);
}
__device__ __forceinline__ unsigned short f2bf(float f) {
    unsigned u = __float_as_uint(f);
    u += 0x7fffu + ((u >> 16) & 1u);
    return (unsigned short)(u >> 16);
}
__device__ __forceinline__ float ldE(const float* p, long i) { return p[i]; }
__device__ __forceinline__ float ldE(const unsigned short* p, long i) { return bf2f(p[i]); }
__device__ __forceinline__ void stE(float* p, long i, float v) { p[i] = v; }
__device__ __forceinline__ void stE(unsigned short* p, long i, float v) { p[i] = f2bf(v); }
__device__ __forceinline__ float ldF(const void* p, long i, int bf) {
    return bf ? bf2f(((const unsigned short*)p)[i]) : ((const float*)p)[i];
}
__device__ __forceinline__ bfrag8 ldfrag(const unsigned short* base, int stride, int lane, int k0) {
    return *(const bfrag8*)(base + (lane & 15) * stride + k0 + ((lane >> 4) << 3));
}

// ---- dtype probe ----
__global__ __launch_bounds__(256) void k_detect(const unsigned short* __restrict__ f,
                                                int* __restrict__ flag) {
    __shared__ int cnt_s;
    if (threadIdx.x == 0) cnt_s = 0;
    __syncthreads();
    int sane = 0;
    for (int j = 0; j < 16; ++j) {
        unsigned short u = f[threadIdx.x * 16 + j];
        int e = (u >> 7) & 255;
        sane += (u == 0 || (e >= 100 && e <= 142)) ? 1 : 0;
    }
    atomicAdd(&cnt_s, sane);
    __syncthreads();
    if (threadIdx.x == 0) *flag = (cnt_s >= 3686) ? 1 : 0;
}

struct WTab {
    const void* src[20];
    int beg[20];
    int end[20];
    int bo[20];
};

__global__ __launch_bounds__(256) void k_cvt_weights(WTab tab, float* __restrict__ ws,
                                                     unsigned short* __restrict__ wsB,
                                                     const int* __restrict__ flagp) {
    int bf = *flagp;
    int gid = blockIdx.x * 256 + threadIdx.x;
    #pragma unroll
    for (int j = 0; j < 20; ++j) {
        if (gid >= tab.beg[j] && gid < tab.end[j]) {
            int off = gid - tab.beg[j];
            float v;
            unsigned short raw;
            if (bf) { raw = ((const unsigned short*)tab.src[j])[off]; v = bf2f(raw); }
            else    { v = ((const float*)tab.src[j])[off]; raw = f2bf(v); }
            ws[gid] = v;
            if (tab.bo[j] >= 0) wsB[tab.bo[j] + off] = raw;
            if (j == 0 && off >= 16384 && off < 32768) {
                int r = (off >> 7) - 128;
                int c = off & 127;
                wsB[B_WKT + c * C + r] = raw;
            }
            if (j == 6) {
                int c = off / 3, comp = off - 3 * c;
                ((float*)(wsB + B_KPW4))[c * 4 + comp] = v;
            }
            if (j == 7) {
                ((float*)(wsB + B_KPW4))[off * 4 + 3] = v;
            }
        }
    }
}

// ---- precompute M[j][h*128+c'] = sum_{d<16} outw[j][h*16+d] wv[h*16+d][c'] ; ob2 ----
__global__ __launch_bounds__(256) void k_mkmat(const float* __restrict__ wsW,
                                               unsigned short* __restrict__ wsBmut) {
    int j = blockIdx.x;            // 0..127
    int t = threadIdx.x;
    const float* outw = wsW + OFF_OUT_W + j * C;
    #pragma unroll
    for (int i = 0; i < 4; ++i) {
        int idx = t + i * 256;     // 0..1023
        int h = idx >> 7, cp = idx & 127;
        float s = 0.f;
        const float* wvh = wsW + OFF_INPROJ_W + (256 + h * 16) * C + cp;
        const float* owh = outw + h * 16;
        #pragma unroll
        for (int d = 0; d < 16; ++d)
            s += owh[d] * wvh[d * C];
        wsBmut[B_M + j * 1024 + idx] = f2bf(s);
    }
    if (t == 0) {
        float s = wsW[OFF_OUT_B + j];
        const float* bv = wsW + OFF_INPROJ_B + 256;
        for (int c = 0; c < C; ++c) s += outw[c] * bv[c];
        ((float*)(wsBmut + B_OB2))[j] = s;
    }
}

// ---- fused coords + qpos + Q projection + per-head qkt precompute (round-10 form) ----
__global__ __launch_bounds__(256) void k_proj(
    const float* __restrict__ wsW, const unsigned short* __restrict__ wsB,
    const void* __restrict__ featv, const int* __restrict__ flagp,
    const int* __restrict__ indices, float* __restrict__ coords,
    unsigned short* __restrict__ Qk)
{
    __shared__ __align__(16) unsigned short sqb[32][136];
    __shared__ __align__(16) unsigned short sqh[32][136];
    __shared__ __align__(16) unsigned short sqk[2][32][136];
    __shared__ float scd[32][4];
    int t = threadIdx.x;
    int row0 = blockIdx.x * 32;
    const int bf = *flagp;
    if (t < 96) {
        int r = t / 3, j = t - 3 * r;
        int n = row0 + r;
        int srci = (j == 0) ? 3 : (j == 1 ? 2 : 1);
        float vs = (j == 2) ? 0.2f : 0.1f;
        float mn = (j == 2) ? -3.0f : -40.0f;
        float v = ((float)indices[n * 4 + srci] + 0.5f) * vs + mn;
        scd[r][j] = v;
        coords[n * 3 + j] = v;
    }
    __syncthreads();
    const float* qpw = wsW + OFF_QPOS_W;
    const float* qpb = wsW + OFF_QPOS_B;
    for (int i = t; i < 32 * C; i += 256) {
        int r = i >> 7, c = i & 127;
        float x = ldF(featv, (long)row0 * C + i, bf);
        float a = qpb[c] + scd[r][0]*qpw[c*3] + scd[r][1]*qpw[c*3+1] + scd[r][2]*qpw[c*3+2];
        sqb[r][c] = f2bf(x + fmaxf(a, 0.0f));
    }
    __syncthreads();
    int lane = t & 63, w = t >> 6;
    int col = lane & 15, quad = lane >> 4;
    for (int tid = w; tid < 16; tid += 4) {
        int mt = tid & 1, nt = tid >> 1, n0 = nt * 16;
        f32x4 acc = {0.f, 0.f, 0.f, 0.f};
        const unsigned short* aB = &sqb[mt*16][0];
        const unsigned short* bB = wsB + B_INPROJ + n0 * C;
        #pragma unroll
        for (int kt = 0; kt < 4; ++kt) {
            bfrag8 a = ldfrag(aB, 136, lane, kt*32);
            bfrag8 b = ldfrag(bB, C, lane, kt*32);
            acc = __builtin_amdgcn_mfma_f32_16x16x32_bf16(a, b, acc, 0, 0, 0);
        }
        #pragma unroll
        for (int r = 0; r < 4; ++r) {
            int n = n0 + col;
            sqh[mt*16 + quad*4 + r][n] = f2bf(acc[r] + wsW[OFF_INPROJ_B + n]);
        }
    }
    __syncthreads();
    const unsigned short* wkT = wsB + B_WKT;
    bfrag8 zf = {0,0,0,0,0,0,0,0};
    for (int h = 0; h < 8; ++h) {
        for (int tid = w; tid < 16; tid += 4) {
            int mt = tid & 1, nt = tid >> 1, n0 = nt * 16;
            bfrag8 a = zf, b = zf;
            if (quad < 2) {
                a = *(const bfrag8*)(&sqh[mt*16 + col][h*16 + quad*8]);
                b = *(const bfrag8*)(wkT + (n0 + col) * C + h*16 + quad*8);
            }
            f32x4 acc = {0.f, 0.f, 0.f, 0.f};
            acc = __builtin_amdgcn_mfma_f32_16x16x32_bf16(a, b, acc, 0, 0, 0);
            #pragma unroll
            for (int r = 0; r < 4; ++r)
                sqk[h & 1][mt*16 + quad*4 + r][n0 + col] = f2bf(acc[r]);
        }
        __syncthreads();
        for (int i = t; i < 2048; i += 256) {
            int r = i >> 6, cp = i & 63;
            unsigned v = *(const unsigned*)&sqk[h & 1][r][2 * cp];
            ((unsigned*)Qk)[(long)(row0 + r) * 512 + h * 64 + cp] = v;
        }
    }
}

// ---- attention: ONE wave per block; outputs z rows (in-place over Qk) ----
// score[h][k] = 0.25 * qkt_h . (x_gk + p_k); z[h] = sum_k attn[h][k] (x_gk + p_k)
__global__ __launch_bounds__(64) void k_attn(
    const float* __restrict__ wsW, const unsigned short* __restrict__ wsB,
    const float* __restrict__ coords, const int* __restrict__ key_idx,
    const void* __restrict__ featv, const int* __restrict__ flagp,
    unsigned short* __restrict__ Qk)
{
    __shared__ __align__(16) unsigned short P[32][136];
    __shared__ __align__(16) unsigned short QZ[8][136];
    __shared__ __align__(16) float SC[8][36];
    __shared__ __align__(16) float REL[32][4];
    __shared__ __align__(16) int   GS[32];

    int l = threadIdx.x;
    int n = blockIdx.x;
    int col = l & 15, quad = l >> 4;
    int c0 = 2 * l;
    const int bf = *flagp;

    const float* kpwp = wsW + OFF_KPOS_W;
    float kw00 = kpwp[c0*3],   kw01 = kpwp[c0*3+1], kw02 = kpwp[c0*3+2];
    float kw10 = kpwp[c0*3+3], kw11 = kpwp[c0*3+4], kw12 = kpwp[c0*3+5];
    float kb0 = wsW[OFF_KPOS_B + c0], kb1 = wsW[OFF_KPOS_B + c0 + 1];

    // Ph0: GS; prefetch qkt A-fragments (coalesced own row); center
    if (l < 32) GS[l] = key_idx[n * K + l];
    float cenx = coords[n*3+0], ceny = coords[n*3+1], cenz = coords[n*3+2];
    bfrag8 ak[4];
    {
        const unsigned short* qkrow = Qk + (long)n * 1024 + (col & 7) * 128;
        #pragma unroll
        for (int ks = 0; ks < 4; ++ks)
            ak[ks] = *(const bfrag8*)(qkrow + ks * 32 + quad * 8);
    }
    // Ph1: rel coords (own-lane GS)
    if (l < 32) {
        int gc = max(GS[l], 0);
        REL[l][0] = coords[gc*3+0] - cenx;
        REL[l][1] = coords[gc*3+1] - ceny;
        REL[l][2] = coords[gc*3+2] - cenz;
        REL[l][3] = 0.f;
    }
    __syncthreads();

    // Ph2: p_full[k][c] = x[g_k][c] + relu(kpos . rel + b)
    if (bf) {
        const unsigned* xb = (const unsigned*)featv;
        #pragma unroll 8
        for (int k = 0; k < K; ++k) {
            int gc = max(GS[k], 0);
            unsigned xv = xb[(long)gc * 64 + l];
            float4 rr = *(const float4*)&REL[k][0];
            float p0 = bf2f((unsigned short)xv)
                     + fmaxf(kb0 + rr.x*kw00 + rr.y*kw01 + rr.z*kw02, 0.f);
            float p1 = bf2f((unsigned short)(xv >> 16))
                     + fmaxf(kb1 + rr.x*kw10 + rr.y*kw11 + rr.z*kw12, 0.f);
            *(unsigned*)&P[k][c0] = (unsigned)f2bf(p0) | ((unsigned)f2bf(p1) << 16);
        }
    } else {
        const float2* xf = (const float2*)featv;
        #pragma unroll 8
        for (int k = 0; k < K; ++k) {
            int gc = max(GS[k], 0);
            float2 xv = xf[(long)gc * 64 + l];
            float4 rr = *(const float4*)&REL[k][0];
            float p0 = xv.x + fmaxf(kb0 + rr.x*kw00 + rr.y*kw01 + rr.z*kw02, 0.f);
            float p1 = xv.y + fmaxf(kb1 + rr.x*kw10 + rr.y*kw11 + rr.z*kw12, 0.f);
            *(unsigned*)&P[k][c0] = (unsigned)f2bf(p0) | ((unsigned)f2bf(p1) << 16);
        }
    }
    __syncthreads();

    // Ph4: scores = qkt . p_full
    #pragma unroll
    for (int nt = 0; nt < 2; ++nt) {
        int g = GS[nt * 16 + col];
        f32x4 acc = {0.f, 0.f, 0.f, 0.f};
        #pragma unroll
        for (int ks = 0; ks < 4; ++ks) {
            bfrag8 bp = *(const bfrag8*)(&P[nt * 16 + col][0] + ks * 32 + quad * 8);
            acc = __builtin_amdgcn_mfma_f32_16x16x32_bf16(ak[ks], bp, acc, 0, 0, 0);
        }
        if (quad < 2) {
            #pragma unroll
            for (int r = 0; r < 4; ++r) {
                int h = quad * 4 + r, k = nt * 16 + col;
                SC[h][k] = (g < 0) ? -1e30f : acc[r] * 0.25f;
            }
        }
    }
    __syncthreads();

    // Ph5: softmax per h
    {
        int h = l >> 3, sub = l & 7;
        float v0 = SC[h][sub],      v1 = SC[h][sub + 8];
        float v2 = SC[h][sub + 16], v3 = SC[h][sub + 24];
        float m = fmaxf(fmaxf(v0, v1), fmaxf(v2, v3));
        m = fmaxf(m, __shfl_xor(m, 1));
        m = fmaxf(m, __shfl_xor(m, 2));
        m = fmaxf(m, __shfl_xor(m, 4));
        float e0 = __expf(v0 - m), e1 = __expf(v1 - m), e2 = __expf(v2 - m), e3 = __expf(v3 - m);
        float s = e0 + e1 + e2 + e3;
        s += __shfl_xor(s, 1);
        s += __shfl_xor(s, 2);
        s += __shfl_xor(s, 4);
        float inv = 1.0f / s;
        SC[h][sub]      = e0 * inv;
        SC[h][sub + 8]  = e1 * inv;
        SC[h][sub + 16] = e2 * inv;
        SC[h][sub + 24] = e3 * inv;
    }
    __syncthreads();

    // Ph6: z[h][c'] = sum_k attn[h][k] p_full[k][c'] -> QZ rows 0-7
    {
        union { bfrag8 f; unsigned short u[8]; } at8;
        #pragma unroll
        for (int j = 0; j < 8; ++j)
            at8.u[j] = f2bf(SC[col & 7][quad * 8 + j]);
        #pragma unroll
        for (int nt = 0; nt < 8; ++nt) {
            union { bfrag8 f; unsigned short u[8]; } bt;
            #pragma unroll
            for (int j = 0; j < 8; ++j)
                bt.u[j] = P[quad * 8 + j][nt * 16 + col];
            f32x4 d = {0.f, 0.f, 0.f, 0.f};
            d = __builtin_amdgcn_mfma_f32_16x16x32_bf16(at8.f, bt.f, d, 0, 0, 0);
            if (quad < 2) {
                #pragma unroll
                for (int r = 0; r < 4; ++r)
                    QZ[quad * 4 + r][nt * 16 + col] = f2bf(d[r]);
            }
        }
    }
    __syncthreads();

    // Ph7: coalesced z store into own Qk row (already consumed at Ph0)
    {
        unsigned* zout = (unsigned*)(Qk + (long)n * 1024);
        #pragma unroll
        for (int j = 0; j < 8; ++j) {
            int idx = l + j * 64;
            zout[idx] = *(const unsigned*)&QZ[idx >> 6][(idx & 63) * 2];
        }
    }
}

// ---- out-proj from z: y1 = feat + z @ M^T + ob2 ; bn1 stats ----
template <typename T>
__global__ __launch_bounds__(256) void k_outproj(
    const float* __restrict__ wsW, const unsigned short* __restrict__ wsB,
    const void* __restrict__ featv, const int* __restrict__ flagp,
    const unsigned short* __restrict__ Z, T* __restrict__ Y, float* __restrict__ acc_s)
{
    __shared__ float syf[32][132];
    int t = threadIdx.x;
    int row0 = blockIdx.x * 32;
    const int bf = *flagp;
    int lane = t & 63, w = t >> 6;
    int col = lane & 15, quad = lane >> 4;
    const unsigned short* M = wsB + B_M;
    const float* ob2 = (const float*)(wsB + B_OB2);
    for (int tid = w; tid < 16; tid += 4) {
        int mt = tid & 1, nt = tid >> 1, n0 = nt * 16;
        f32x4 acc = {0.f, 0.f, 0.f, 0.f};
        const unsigned short* zrow = Z + (long)(row0 + mt*16 + col) * 1024 + quad * 8;
        const unsigned short* mrow = M + (n0 + col) * 1024 + quad * 8;
        #pragma unroll 8
        for (int kt = 0; kt < 32; ++kt) {
            bfrag8 a = *(const bfrag8*)(zrow + kt * 32);
            bfrag8 b = *(const bfrag8*)(mrow + kt * 32);
            acc = __builtin_amdgcn_mfma_f32_16x16x32_bf16(a, b, acc, 0, 0, 0);
        }
        #pragma unroll
        for (int r = 0; r < 4; ++r) {
            int m = mt*16 + quad*4 + r;
            int n = n0 + col;
            syf[m][n] = acc[r] + ob2[n] + ldF(featv, (long)(row0+m)*C + n, bf);
        }
    }
    __syncthreads();
    for (int i = t; i < 32 * C; i += 256)
        stE(Y, (long)row0 * C + i, syf[i>>7][i&127]);
    if (t < C) {
        float s = 0.f, sq = 0.f;
        for (int r = 0; r < 32; ++r) { float v = syf[r][t]; s += v; sq += v*v; }
        atomicAdd(&acc_s[t], s);
        atomicAdd(&acc_s[C + t], sq);
    }
}

// ---- bn1 + FFN + residual + bn2 stats (MFMA) ----
template <typename T>
__global__ __launch_bounds__(256) void k_ffn(
    const float* __restrict__ wsW, const unsigned short* __restrict__ wsB,
    T* __restrict__ Y, const float* __restrict__ acc1, float* __restrict__ acc2)
{
    __shared__ __align__(16) unsigned short sxb[32][136];
    __shared__ __align__(16) unsigned short sh[32][520];
    __shared__ float nsc[C], nsh[C];
    float (*syf)[132] = (float(*)[132])sh;
    int t = threadIdx.x;
    int row0 = blockIdx.x * 32;
    if (t < C) {
        float m = acc1[t] * (1.0f/NPTS);
        float v = acc1[C+t] * (1.0f/NPTS) - m*m;
        float rs = rsqrtf(v + EPS);
        float sc = rs * wsW[OFF_N1G + t];
        nsc[t] = sc;
        nsh[t] = wsW[OFF_N1B + t] - m * sc;
    }
    __syncthreads();
    for (int i = t; i < 32 * C; i += 256) {
        int c = i & 127;
        sxb[i>>7][c] = f2bf(ldE(Y, (long)row0 * C + i) * nsc[c] + nsh[c]);
    }
    __syncthreads();
    int lane = t & 63, w = t >> 6;
    int col = lane & 15, quad = lane >> 4;
    for (int tid = w; tid < 64; tid += 4) {
        int mt = tid & 1, nt = tid >> 1, n0 = nt * 16;
        f32x4 acc = {0.f, 0.f, 0.f, 0.f};
        const unsigned short* aB = &sxb[mt*16][0];
        const unsigned short* bB = wsB + B_LIN1 + n0 * C;
        #pragma unroll
        for (int kt = 0; kt < 4; ++kt) {
            bfrag8 a = ldfrag(aB, 136, lane, kt*32);
            bfrag8 b = ldfrag(bB, C, lane, kt*32);
            acc = __builtin_amdgcn_mfma_f32_16x16x32_bf16(a, b, acc, 0, 0, 0);
        }
        #pragma unroll
        for (int r = 0; r < 4; ++r) {
            int m = mt*16 + quad*4 + r;
            int n = n0 + col;
            sh[m][n] = f2bf(fmaxf(acc[r] + wsW[OFF_LIN1_B + n], 0.f));
        }
    }
    __syncthreads();
    f32x4 accT[4];
    #pragma unroll
    for (int i = 0; i < 4; ++i) {
        int tid = w + 4*i;
        int mt = tid & 1, nt = tid >> 1, n0 = nt * 16;
        f32x4 acc = {0.f, 0.f, 0.f, 0.f};
        const unsigned short* aB = &sh[mt*16][0];
        const unsigned short* bB = wsB + B_LIN2 + n0 * FF;
        #pragma unroll
        for (int kt = 0; kt < 16; ++kt) {
            bfrag8 a = ldfrag(aB, 520, lane, kt*32);
            bfrag8 b = ldfrag(bB, FF, lane, kt*32);
            acc = __builtin_amdgcn_mfma_f32_16x16x32_bf16(a, b, acc, 0, 0, 0);
        }
        accT[i] = acc;
    }
    __syncthreads();
    #pragma unroll
    for (int i = 0; i < 4; ++i) {
        int tid = w + 4*i;
        int mt = tid & 1, nt = tid >> 1, n0 = nt * 16;
        #pragma unroll
        for (int r = 0; r < 4; ++r) {
            int m = mt*16 + quad*4 + r;
            int n = n0 + col;
            syf[m][n] = accT[i][r] + wsW[OFF_LIN2_B + n] + bf2f(sxb[m][n]);
        }
    }
    __syncthreads();
    for (int i = t; i < 32 * C; i += 256)
        stE(Y, (long)row0 * C + i, syf[i>>7][i&127]);
    if (t < C) {
        float s = 0.f, sq = 0.f;
        for (int r = 0; r < 32; ++r) { float v = syf[r][t]; s += v; sq += v*v; }
        atomicAdd(&acc2[t], s);
        atomicAdd(&acc2[C+t], sq);
    }
}

// ---- bn2 + output linear + bn3 stats (MFMA) ----
template <typename T>
__global__ __launch_bounds__(256) void k_outl(
    const float* __restrict__ wsW, const unsigned short* __restrict__ wsB,
    T* __restrict__ Y, const float* __restrict__ acc2, float* __restrict__ acc3)
{
    __shared__ __align__(16) unsigned short sxb[32][136];
    __shared__ float syf[32][132];
    __shared__ float nsc[C], nsh[C];
    int t = threadIdx.x;
    int row0 = blockIdx.x * 32;
    if (t < C) {
        float m = acc2[t] * (1.0f/NPTS);
        float v = acc2[C+t] * (1.0f/NPTS) - m*m;
        float rs = rsqrtf(v + EPS);
        float sc = rs * wsW[OFF_N2G + t];
        nsc[t] = sc;
        nsh[t] = wsW[OFF_N2B + t] - m * sc;
    }
    __syncthreads();
    for (int i = t; i < 32 * C; i += 256) {
        int c = i & 127;
        sxb[i>>7][c] = f2bf(ldE(Y, (long)row0 * C + i) * nsc[c] + nsh[c]);
    }
    __syncthreads();
    int lane = t & 63, w = t >> 6;
    int col = lane & 15, quad = lane >> 4;
    for (int tid = w; tid < 16; tid += 4) {
        int mt = tid & 1, nt = tid >> 1, n0 = nt * 16;
        f32x4 acc = {0.f, 0.f, 0.f, 0.f};
        const unsigned short* aB = &sxb[mt*16][0];
        const unsigned short* bB = wsB + B_OUTL + n0 * C;
        #pragma unroll
        for (int kt = 0; kt < 4; ++kt) {
            bfrag8 a = ldfrag(aB, 136, lane, kt*32);
            bfrag8 b = ldfrag(bB, C, lane, kt*32);
            acc = __builtin_amdgcn_mfma_f32_16x16x32_bf16(a, b, acc, 0, 0, 0);
        }
        #pragma unroll
        for (int r = 0; r < 4; ++r) {
            int m = mt*16 + quad*4 + r;
            int n = n0 + col;
            syf[m][n] = acc[r] + wsW[OFF_OUTL_B + n];
        }
    }
    __syncthreads();
    for (int i = t; i < 32 * CO; i += 256)
        stE(Y, (long)row0 * CO + i, syf[i>>7][i&127]);
    if (t < CO) {
        float s = 0.f, sq = 0.f;
        for (int r = 0; r < 32; ++r) { float v = syf[r][t]; s += v; sq += v*v; }
        atomicAdd(&acc3[t], s);
        atomicAdd(&acc3[CO+t], sq);
    }
}

// ---- final BN + relu -> output ----
template <typename T>
__global__ __launch_bounds__(256) void k_final(
    const float* __restrict__ wsW, const T* __restrict__ Y,
    const float* __restrict__ acc3, const int* __restrict__ flagp,
    void* __restrict__ out)
{
    long i = (long)blockIdx.x * 256 + threadIdx.x;
    int c = (int)(i & (CO-1));
    float m = acc3[c] * (1.0f/NPTS);
    float v = acc3[CO+c] * (1.0f/NPTS) - m*m;
    float rs = rsqrtf(v + EPS);
    float y = (ldE(Y, i) - m) * rs * wsW[OFF_BOG + c] + wsW[OFF_BOB + c];
    y = fmaxf(y, 0.f);
    if (*flagp) ((unsigned short*)out)[i] = f2bf(y);
    else        ((float*)out)[i] = y;
}

extern "C" void kernel_launch(void* const* d_in, const int* in_sizes, int n_in,
                              void* d_out, int out_size, void* d_ws, size_t ws_size,
                              hipStream_t stream)
{
    char* base = (char*)d_ws;
    float* wsW = (float*)base;
    float* acc1 = wsW + WTOTAL;
    float* acc2 = acc1 + 256;
    float* acc3 = acc2 + 256;
    int* flagp = (int*)(wsW + WTOTAL + 768);
    float* coords = wsW + WTOTAL + 776;
    unsigned short* wsB = (unsigned short*)(base + OFF_WB_BYTES);

    const void* featv = d_in[0];
    const int* indices = (const int*)d_in[1];
    const int* key_idx = (const int*)d_in[2];

    hipMemsetAsync(acc1, 0, 768 * sizeof(float), stream);
    k_detect<<<1, 256, 0, stream>>>((const unsigned short*)d_in[0], flagp);

    static const int cnt[20] = {49152,384,16384,128,384,128,384,128,128,128,
                                128,128,65536,512,65536,128,16384,128,128,128};
    static const int bofs[20] = {B_INPROJ,-1,B_OUTW,-1,-1,-1,-1,-1,-1,-1,
                                 -1,-1,B_LIN1,-1,B_LIN2,-1,B_OUTL,-1,-1,-1};
    WTab tab;
    int off = 0;
    for (int j = 0; j < 20; ++j) {
        tab.src[j] = d_in[3 + j];
        tab.beg[j] = off;
        tab.end[j] = off + cnt[j];
        tab.bo[j] = bofs[j];
        off += cnt[j];
    }
    k_cvt_weights<<<WTOTAL/256, 256, 0, stream>>>(tab, wsW, wsB, flagp);
    k_mkmat<<<128, 256, 0, stream>>>(wsW, wsB);

    size_t bigN = (size_t)NPTS * C;
    bool f32mode = (ws_size >= OFF_BIG_BYTES + QK_BYTES + bigN * 4);

    unsigned short* Qk = (unsigned short*)(base + OFF_BIG_BYTES);

    k_proj<<<NPTS/32, 256, 0, stream>>>(wsW, wsB, featv, flagp, indices, coords, Qk);
    k_attn<<<NPTS, 64, 0, stream>>>(wsW, wsB, coords, key_idx, featv, flagp, Qk);

    if (f32mode) {
        float* Y = (float*)(base + OFF_BIG_BYTES + QK_BYTES);
        k_outproj<float><<<NPTS/32, 256, 0, stream>>>(wsW, wsB, featv, flagp, Qk, Y, acc1);
        k_ffn<float><<<NPTS/32, 256, 0, stream>>>(wsW, wsB, Y, acc1, acc2);
        k_outl<float><<<NPTS/32, 256, 0, stream>>>(wsW, wsB, Y, acc2, acc3);
        k_final<float><<<(NPTS*CO)/256, 256, 0, stream>>>(wsW, Y, acc3, flagp, d_out);
    } else {
        unsigned short* Y = (unsigned short*)(base + OFF_BIG_BYTES + QK_BYTES);
        k_outproj<unsigned short><<<NPTS/32, 256, 0, stream>>>(wsW, wsB, featv, flagp, Qk, Y, acc1);
        k_ffn<unsigned short><<<NPTS/32, 256, 0, stream>>>(wsW, wsB, Y, acc1, acc2);
        k_outl<unsigned short><<<NPTS/32, 256, 0, stream>>>(wsW, wsB, Y, acc2, acc3);
        k_final<unsigned short><<<(NPTS*CO)/256, 256, 0, stream>>>(wsW, Y, acc3, flagp, d_out);
    }
}

// Round 13
// 724.100 us; speedup vs baseline: 1.2594x; 1.1053x over previous
//
#include <hip/hip_runtime.h>

#define NPTS 60000
#define C 128
#define K 32
#define FF 512
#define CO 128
#define H 8
#define DH 16
#define EPS 1e-5f

// ---- fp32 weight layout (float elements) ----
constexpr int OFF_INPROJ_W = 0;          // 384*128
constexpr int OFF_INPROJ_B = 49152;      // 384
constexpr int OFF_OUT_W    = 49536;      // 16384
constexpr int OFF_OUT_B    = 65920;      // 128
constexpr int OFF_QPOS_W   = 66048;      // 384
constexpr int OFF_QPOS_B   = 66432;      // 128
constexpr int OFF_KPOS_W   = 66560;      // 384
constexpr int OFF_KPOS_B   = 66944;      // 128
constexpr int OFF_N1G      = 67072;
constexpr int OFF_N1B      = 67200;
constexpr int OFF_N2G      = 67328;
constexpr int OFF_N2B      = 67456;
constexpr int OFF_LIN1_W   = 67584;      // 65536
constexpr int OFF_LIN1_B   = 133120;     // 512
constexpr int OFF_LIN2_W   = 133632;     // 65536
constexpr int OFF_LIN2_B   = 199168;     // 128
constexpr int OFF_OUTL_W   = 199296;     // 16384
constexpr int OFF_OUTL_B   = 215680;     // 128
constexpr int OFF_BOG      = 215808;
constexpr int OFF_BOB      = 215936;
constexpr int WTOTAL       = 216064;

// ---- bf16 weight copies (ushort elements within wsB) ----
constexpr int B_INPROJ = 0;        // 384x128
constexpr int B_OUTW   = 49152;    // 128x128 (layout keep)
constexpr int B_LIN1   = 65536;    // 512x128
constexpr int B_LIN2   = 131072;   // 128x512
constexpr int B_OUTL   = 196608;   // 128x128
constexpr int B_WKT    = 212992;   // 128x128
constexpr int B_KPW4   = 229376;   // 128 x float4 (fp32, 2048 B)
constexpr int B_M      = 230400;   // 128x1024 bf16 fused (outw ⊗ blockdiag wv)
constexpr int B_OB2    = 361472;   // 128 fp32: out_b + outw@bv
constexpr size_t OFF_WB_BYTES  = 1587456;
constexpr size_t OFF_BIG_BYTES = 2310912;
constexpr size_t QK_BYTES = (size_t)NPTS * 1024 * 2;   // qkt rows; reused as z rows

typedef __attribute__((ext_vector_type(8))) short bfrag8;
typedef __attribute__((ext_vector_type(4))) float f32x4;

__device__ __forceinline__ float bf2f(unsigned short s) {
    return __uint_as_float(((unsigned)s) << 16);
}
__device__ __forceinline__ unsigned short f2bf(float f) {
    unsigned u = __float_as_uint(f);
    u += 0x7fffu + ((u >> 16) & 1u);
    return (unsigned short)(u >> 16);
}
__device__ __forceinline__ float ldE(const float* p, long i) { return p[i]; }
__device__ __forceinline__ float ldE(const unsigned short* p, long i) { return bf2f(p[i]); }
__device__ __forceinline__ void stE(float* p, long i, float v) { p[i] = v; }
__device__ __forceinline__ void stE(unsigned short* p, long i, float v) { p[i] = f2bf(v); }
__device__ __forceinline__ float ldF(const void* p, long i, int bf) {
    return bf ? bf2f(((const unsigned short*)p)[i]) : ((const float*)p)[i];
}
__device__ __forceinline__ bfrag8 ldfrag(const unsigned short* base, int stride, int lane, int k0) {
    return *(const bfrag8*)(base + (lane & 15) * stride + k0 + ((lane >> 4) << 3));
}

// ---- dtype probe ----
__global__ __launch_bounds__(256) void k_detect(const unsigned short* __restrict__ f,
                                                int* __restrict__ flag) {
    __shared__ int cnt_s;
    if (threadIdx.x == 0) cnt_s = 0;
    __syncthreads();
    int sane = 0;
    for (int j = 0; j < 16; ++j) {
        unsigned short u = f[threadIdx.x * 16 + j];
        int e = (u >> 7) & 255;
        sane += (u == 0 || (e >= 100 && e <= 142)) ? 1 : 0;
    }
    atomicAdd(&cnt_s, sane);
    __syncthreads();
    if (threadIdx.x == 0) *flag = (cnt_s >= 3686) ? 1 : 0;
}

struct WTab {
    const void* src[20];
    int beg[20];
    int end[20];
    int bo[20];
};

__global__ __launch_bounds__(256) void k_cvt_weights(WTab tab, float* __restrict__ ws,
                                                     unsigned short* __restrict__ wsB,
                                                     const int* __restrict__ flagp) {
    int bf = *flagp;
    int gid = blockIdx.x * 256 + threadIdx.x;
    #pragma unroll
    for (int j = 0; j < 20; ++j) {
        if (gid >= tab.beg[j] && gid < tab.end[j]) {
            int off = gid - tab.beg[j];
            float v;
            unsigned short raw;
            if (bf) { raw = ((const unsigned short*)tab.src[j])[off]; v = bf2f(raw); }
            else    { v = ((const float*)tab.src[j])[off]; raw = f2bf(v); }
            ws[gid] = v;
            if (tab.bo[j] >= 0) wsB[tab.bo[j] + off] = raw;
            if (j == 0 && off >= 16384 && off < 32768) {
                int r = (off >> 7) - 128;
                int c = off & 127;
                wsB[B_WKT + c * C + r] = raw;
            }
            if (j == 6) {
                int c = off / 3, comp = off - 3 * c;
                ((float*)(wsB + B_KPW4))[c * 4 + comp] = v;
            }
            if (j == 7) {
                ((float*)(wsB + B_KPW4))[off * 4 + 3] = v;
            }
        }
    }
}

// ---- precompute M[j][h*128+c'] = sum_{d<16} outw[j][h*16+d] wv[h*16+d][c'] ; ob2 ----
__global__ __launch_bounds__(256) void k_mkmat(const float* __restrict__ wsW,
                                               unsigned short* __restrict__ wsBmut) {
    int j = blockIdx.x;
    int t = threadIdx.x;
    const float* outw = wsW + OFF_OUT_W + j * C;
    #pragma unroll
    for (int i = 0; i < 4; ++i) {
        int idx = t + i * 256;
        int h = idx >> 7, cp = idx & 127;
        float s = 0.f;
        const float* wvh = wsW + OFF_INPROJ_W + (256 + h * 16) * C + cp;
        const float* owh = outw + h * 16;
        #pragma unroll
        for (int d = 0; d < 16; ++d)
            s += owh[d] * wvh[d * C];
        wsBmut[B_M + j * 1024 + idx] = f2bf(s);
    }
    if (t == 0) {
        float s = wsW[OFF_OUT_B + j];
        const float* bv = wsW + OFF_INPROJ_B + 256;
        for (int c = 0; c < C; ++c) s += outw[c] * bv[c];
        ((float*)(wsBmut + B_OB2))[j] = s;
    }
}

// ---- fused coords + qpos + Q projection + per-head qkt precompute ----
__global__ __launch_bounds__(256) void k_proj(
    const float* __restrict__ wsW, const unsigned short* __restrict__ wsB,
    const void* __restrict__ featv, const int* __restrict__ flagp,
    const int* __restrict__ indices, float* __restrict__ coords,
    unsigned short* __restrict__ Qk)
{
    __shared__ __align__(16) unsigned short sqb[32][136];
    __shared__ __align__(16) unsigned short sqh[32][136];
    __shared__ __align__(16) unsigned short sqk[2][32][136];
    __shared__ float scd[32][4];
    int t = threadIdx.x;
    int row0 = blockIdx.x * 32;
    const int bf = *flagp;
    if (t < 96) {
        int r = t / 3, j = t - 3 * r;
        int n = row0 + r;
        int srci = (j == 0) ? 3 : (j == 1 ? 2 : 1);
        float vs = (j == 2) ? 0.2f : 0.1f;
        float mn = (j == 2) ? -3.0f : -40.0f;
        float v = ((float)indices[n * 4 + srci] + 0.5f) * vs + mn;
        scd[r][j] = v;
        coords[n * 3 + j] = v;
    }
    __syncthreads();
    const float* qpw = wsW + OFF_QPOS_W;
    const float* qpb = wsW + OFF_QPOS_B;
    for (int i = t; i < 32 * C; i += 256) {
        int r = i >> 7, c = i & 127;
        float x = ldF(featv, (long)row0 * C + i, bf);
        float a = qpb[c] + scd[r][0]*qpw[c*3] + scd[r][1]*qpw[c*3+1] + scd[r][2]*qpw[c*3+2];
        sqb[r][c] = f2bf(x + fmaxf(a, 0.0f));
    }
    __syncthreads();
    int lane = t & 63, w = t >> 6;
    int col = lane & 15, quad = lane >> 4;
    for (int tid = w; tid < 16; tid += 4) {
        int mt = tid & 1, nt = tid >> 1, n0 = nt * 16;
        f32x4 acc = {0.f, 0.f, 0.f, 0.f};
        const unsigned short* aB = &sqb[mt*16][0];
        const unsigned short* bB = wsB + B_INPROJ + n0 * C;
        #pragma unroll
        for (int kt = 0; kt < 4; ++kt) {
            bfrag8 a = ldfrag(aB, 136, lane, kt*32);
            bfrag8 b = ldfrag(bB, C, lane, kt*32);
            acc = __builtin_amdgcn_mfma_f32_16x16x32_bf16(a, b, acc, 0, 0, 0);
        }
        #pragma unroll
        for (int r = 0; r < 4; ++r) {
            int n = n0 + col;
            sqh[mt*16 + quad*4 + r][n] = f2bf(acc[r] + wsW[OFF_INPROJ_B + n]);
        }
    }
    __syncthreads();
    const unsigned short* wkT = wsB + B_WKT;
    bfrag8 zf = {0,0,0,0,0,0,0,0};
    for (int h = 0; h < 8; ++h) {
        for (int tid = w; tid < 16; tid += 4) {
            int mt = tid & 1, nt = tid >> 1, n0 = nt * 16;
            bfrag8 a = zf, b = zf;
            if (quad < 2) {
                a = *(const bfrag8*)(&sqh[mt*16 + col][h*16 + quad*8]);
                b = *(const bfrag8*)(wkT + (n0 + col) * C + h*16 + quad*8);
            }
            f32x4 acc = {0.f, 0.f, 0.f, 0.f};
            acc = __builtin_amdgcn_mfma_f32_16x16x32_bf16(a, b, acc, 0, 0, 0);
            #pragma unroll
            for (int r = 0; r < 4; ++r)
                sqk[h & 1][mt*16 + quad*4 + r][n0 + col] = f2bf(acc[r]);
        }
        __syncthreads();
        for (int i = t; i < 2048; i += 256) {
            int r = i >> 6, cp = i & 63;
            unsigned v = *(const unsigned*)&sqk[h & 1][r][2 * cp];
            ((unsigned*)Qk)[(long)(row0 + r) * 512 + h * 64 + cp] = v;
        }
    }
}

// ---- attention: ONE wave per block; outputs z rows (in-place over Qk) ----
__global__ __launch_bounds__(64) void k_attn(
    const float* __restrict__ wsW, const unsigned short* __restrict__ wsB,
    const float* __restrict__ coords, const int* __restrict__ key_idx,
    const void* __restrict__ featv, const int* __restrict__ flagp,
    unsigned short* __restrict__ Qk)
{
    __shared__ __align__(16) unsigned short P[32][136];
    __shared__ __align__(16) unsigned short QZ[8][136];
    __shared__ __align__(16) float SC[8][36];
    __shared__ __align__(16) float REL[32][4];
    __shared__ __align__(16) int   GS[32];

    int l = threadIdx.x;
    int n = blockIdx.x;
    int col = l & 15, quad = l >> 4;
    int c0 = 2 * l;
    const int bf = *flagp;

    const float* kpwp = wsW + OFF_KPOS_W;
    float kw00 = kpwp[c0*3],   kw01 = kpwp[c0*3+1], kw02 = kpwp[c0*3+2];
    float kw10 = kpwp[c0*3+3], kw11 = kpwp[c0*3+4], kw12 = kpwp[c0*3+5];
    float kb0 = wsW[OFF_KPOS_B + c0], kb1 = wsW[OFF_KPOS_B + c0 + 1];

    if (l < 32) GS[l] = key_idx[n * K + l];
    float cenx = coords[n*3+0], ceny = coords[n*3+1], cenz = coords[n*3+2];
    bfrag8 ak[4];
    {
        const unsigned short* qkrow = Qk + (long)n * 1024 + (col & 7) * 128;
        #pragma unroll
        for (int ks = 0; ks < 4; ++ks)
            ak[ks] = *(const bfrag8*)(qkrow + ks * 32 + quad * 8);
    }
    if (l < 32) {
        int gc = max(GS[l], 0);
        REL[l][0] = coords[gc*3+0] - cenx;
        REL[l][1] = coords[gc*3+1] - ceny;
        REL[l][2] = coords[gc*3+2] - cenz;
        REL[l][3] = 0.f;
    }
    __syncthreads();

    if (bf) {
        const unsigned* xb = (const unsigned*)featv;
        #pragma unroll 8
        for (int k = 0; k < K; ++k) {
            int gc = max(GS[k], 0);
            unsigned xv = xb[(long)gc * 64 + l];
            float4 rr = *(const float4*)&REL[k][0];
            float p0 = bf2f((unsigned short)xv)
                     + fmaxf(kb0 + rr.x*kw00 + rr.y*kw01 + rr.z*kw02, 0.f);
            float p1 = bf2f((unsigned short)(xv >> 16))
                     + fmaxf(kb1 + rr.x*kw10 + rr.y*kw11 + rr.z*kw12, 0.f);
            *(unsigned*)&P[k][c0] = (unsigned)f2bf(p0) | ((unsigned)f2bf(p1) << 16);
        }
    } else {
        const float2* xf = (const float2*)featv;
        #pragma unroll 8
        for (int k = 0; k < K; ++k) {
            int gc = max(GS[k], 0);
            float2 xv = xf[(long)gc * 64 + l];
            float4 rr = *(const float4*)&REL[k][0];
            float p0 = xv.x + fmaxf(kb0 + rr.x*kw00 + rr.y*kw01 + rr.z*kw02, 0.f);
            float p1 = xv.y + fmaxf(kb1 + rr.x*kw10 + rr.y*kw11 + rr.z*kw12, 0.f);
            *(unsigned*)&P[k][c0] = (unsigned)f2bf(p0) | ((unsigned)f2bf(p1) << 16);
        }
    }
    __syncthreads();

    #pragma unroll
    for (int nt = 0; nt < 2; ++nt) {
        int g = GS[nt * 16 + col];
        f32x4 acc = {0.f, 0.f, 0.f, 0.f};
        #pragma unroll
        for (int ks = 0; ks < 4; ++ks) {
            bfrag8 bp = *(const bfrag8*)(&P[nt * 16 + col][0] + ks * 32 + quad * 8);
            acc = __builtin_amdgcn_mfma_f32_16x16x32_bf16(ak[ks], bp, acc, 0, 0, 0);
        }
        if (quad < 2) {
            #pragma unroll
            for (int r = 0; r < 4; ++r) {
                int h = quad * 4 + r, k = nt * 16 + col;
                SC[h][k] = (g < 0) ? -1e30f : acc[r] * 0.25f;
            }
        }
    }
    __syncthreads();

    {
        int h = l >> 3, sub = l & 7;
        float v0 = SC[h][sub],      v1 = SC[h][sub + 8];
        float v2 = SC[h][sub + 16], v3 = SC[h][sub + 24];
        float m = fmaxf(fmaxf(v0, v1), fmaxf(v2, v3));
        m = fmaxf(m, __shfl_xor(m, 1));
        m = fmaxf(m, __shfl_xor(m, 2));
        m = fmaxf(m, __shfl_xor(m, 4));
        float e0 = __expf(v0 - m), e1 = __expf(v1 - m), e2 = __expf(v2 - m), e3 = __expf(v3 - m);
        float s = e0 + e1 + e2 + e3;
        s += __shfl_xor(s, 1);
        s += __shfl_xor(s, 2);
        s += __shfl_xor(s, 4);
        float inv = 1.0f / s;
        SC[h][sub]      = e0 * inv;
        SC[h][sub + 8]  = e1 * inv;
        SC[h][sub + 16] = e2 * inv;
        SC[h][sub + 24] = e3 * inv;
    }
    __syncthreads();

    {
        union { bfrag8 f; unsigned short u[8]; } at8;
        #pragma unroll
        for (int j = 0; j < 8; ++j)
            at8.u[j] = f2bf(SC[col & 7][quad * 8 + j]);
        #pragma unroll
        for (int nt = 0; nt < 8; ++nt) {
            union { bfrag8 f; unsigned short u[8]; } bt;
            #pragma unroll
            for (int j = 0; j < 8; ++j)
                bt.u[j] = P[quad * 8 + j][nt * 16 + col];
            f32x4 d = {0.f, 0.f, 0.f, 0.f};
            d = __builtin_amdgcn_mfma_f32_16x16x32_bf16(at8.f, bt.f, d, 0, 0, 0);
            if (quad < 2) {
                #pragma unroll
                for (int r = 0; r < 4; ++r)
                    QZ[quad * 4 + r][nt * 16 + col] = f2bf(d[r]);
            }
        }
    }
    __syncthreads();

    {
        unsigned* zout = (unsigned*)(Qk + (long)n * 1024);
        #pragma unroll
        for (int j = 0; j < 8; ++j) {
            int idx = l + j * 64;
            zout[idx] = *(const unsigned*)&QZ[idx >> 6][(idx & 63) * 2];
        }
    }
}

// ---- out-proj from z: y1 = feat + z @ M^T + ob2 ; bn1 stats ----
// kt-chunked: 8 A-frags register-cached, reused across the wave's 4 nt-tiles.
template <typename T>
__global__ __launch_bounds__(256) void k_outproj(
    const float* __restrict__ wsW, const unsigned short* __restrict__ wsB,
    const void* __restrict__ featv, const int* __restrict__ flagp,
    const unsigned short* __restrict__ Z, T* __restrict__ Y, float* __restrict__ acc_s)
{
    __shared__ float syf[32][132];
    int t = threadIdx.x;
    int row0 = blockIdx.x * 32;
    const int bf = *flagp;
    int lane = t & 63, w = t >> 6;
    int col = lane & 15, quad = lane >> 4;
    const unsigned short* M = wsB + B_M;
    const float* ob2 = (const float*)(wsB + B_OB2);
    int mt = w & 1, ntb = w >> 1;           // wave's tiles: (mt, ntb + 2*i), i=0..3
    f32x4 acc[4] = {{0,0,0,0},{0,0,0,0},{0,0,0,0},{0,0,0,0}};
    const unsigned short* zrow = Z + (long)(row0 + mt*16 + col) * 1024 + quad * 8;
    #pragma unroll
    for (int ktc = 0; ktc < 4; ++ktc) {
        bfrag8 a[8];
        #pragma unroll
        for (int j = 0; j < 8; ++j)
            a[j] = *(const bfrag8*)(zrow + (ktc * 8 + j) * 32);
        #pragma unroll
        for (int i = 0; i < 4; ++i) {
            int n0 = (ntb + 2 * i) * 16;
            const unsigned short* mrow = M + (n0 + col) * 1024 + quad * 8;
            #pragma unroll
            for (int j = 0; j < 8; ++j) {
                bfrag8 b = *(const bfrag8*)(mrow + (ktc * 8 + j) * 32);
                acc[i] = __builtin_amdgcn_mfma_f32_16x16x32_bf16(a[j], b, acc[i], 0, 0, 0);
            }
        }
    }
    #pragma unroll
    for (int i = 0; i < 4; ++i) {
        int n0 = (ntb + 2 * i) * 16;
        #pragma unroll
        for (int r = 0; r < 4; ++r) {
            int m = mt*16 + quad*4 + r;
            int n = n0 + col;
            syf[m][n] = acc[i][r] + ob2[n] + ldF(featv, (long)(row0+m)*C + n, bf);
        }
    }
    __syncthreads();
    for (int i = t; i < 32 * C; i += 256)
        stE(Y, (long)row0 * C + i, syf[i>>7][i&127]);
    if (t < C) {
        float s = 0.f, sq = 0.f;
        for (int r = 0; r < 32; ++r) { float v = syf[r][t]; s += v; sq += v*v; }
        atomicAdd(&acc_s[t], s);
        atomicAdd(&acc_s[C + t], sq);
    }
}

// ---- bn1 + FFN + residual + bn2 stats (MFMA) ----
template <typename T>
__global__ __launch_bounds__(256) void k_ffn(
    const float* __restrict__ wsW, const unsigned short* __restrict__ wsB,
    T* __restrict__ Y, const float* __restrict__ acc1, float* __restrict__ acc2)
{
    __shared__ __align__(16) unsigned short sxb[32][136];
    __shared__ __align__(16) unsigned short sh[32][520];
    __shared__ float nsc[C], nsh[C];
    float (*syf)[132] = (float(*)[132])sh;
    int t = threadIdx.x;
    int row0 = blockIdx.x * 32;
    if (t < C) {
        float m = acc1[t] * (1.0f/NPTS);
        float v = acc1[C+t] * (1.0f/NPTS) - m*m;
        float rs = rsqrtf(v + EPS);
        float sc = rs * wsW[OFF_N1G + t];
        nsc[t] = sc;
        nsh[t] = wsW[OFF_N1B + t] - m * sc;
    }
    __syncthreads();
    for (int i = t; i < 32 * C; i += 256) {
        int c = i & 127;
        sxb[i>>7][c] = f2bf(ldE(Y, (long)row0 * C + i) * nsc[c] + nsh[c]);
    }
    __syncthreads();
    int lane = t & 63, w = t >> 6;
    int col = lane & 15, quad = lane >> 4;
    for (int tid = w; tid < 64; tid += 4) {
        int mt = tid & 1, nt = tid >> 1, n0 = nt * 16;
        f32x4 acc = {0.f, 0.f, 0.f, 0.f};
        const unsigned short* aB = &sxb[mt*16][0];
        const unsigned short* bB = wsB + B_LIN1 + n0 * C;
        #pragma unroll
        for (int kt = 0; kt < 4; ++kt) {
            bfrag8 a = ldfrag(aB, 136, lane, kt*32);
            bfrag8 b = ldfrag(bB, C, lane, kt*32);
            acc = __builtin_amdgcn_mfma_f32_16x16x32_bf16(a, b, acc, 0, 0, 0);
        }
        #pragma unroll
        for (int r = 0; r < 4; ++r) {
            int m = mt*16 + quad*4 + r;
            int n = n0 + col;
            sh[m][n] = f2bf(fmaxf(acc[r] + wsW[OFF_LIN1_B + n], 0.f));
        }
    }
    __syncthreads();
    f32x4 accT[4];
    #pragma unroll
    for (int i = 0; i < 4; ++i) {
        int tid = w + 4*i;
        int mt = tid & 1, nt = tid >> 1, n0 = nt * 16;
        f32x4 acc = {0.f, 0.f, 0.f, 0.f};
        const unsigned short* aB = &sh[mt*16][0];
        const unsigned short* bB = wsB + B_LIN2 + n0 * FF;
        #pragma unroll
        for (int kt = 0; kt < 16; ++kt) {
            bfrag8 a = ldfrag(aB, 520, lane, kt*32);
            bfrag8 b = ldfrag(bB, FF, lane, kt*32);
            acc = __builtin_amdgcn_mfma_f32_16x16x32_bf16(a, b, acc, 0, 0, 0);
        }
        accT[i] = acc;
    }
    __syncthreads();
    #pragma unroll
    for (int i = 0; i < 4; ++i) {
        int tid = w + 4*i;
        int mt = tid & 1, nt = tid >> 1, n0 = nt * 16;
        #pragma unroll
        for (int r = 0; r < 4; ++r) {
            int m = mt*16 + quad*4 + r;
            int n = n0 + col;
            syf[m][n] = accT[i][r] + wsW[OFF_LIN2_B + n] + bf2f(sxb[m][n]);
        }
    }
    __syncthreads();
    for (int i = t; i < 32 * C; i += 256)
        stE(Y, (long)row0 * C + i, syf[i>>7][i&127]);
    if (t < C) {
        float s = 0.f, sq = 0.f;
        for (int r = 0; r < 32; ++r) { float v = syf[r][t]; s += v; sq += v*v; }
        atomicAdd(&acc2[t], s);
        atomicAdd(&acc2[C+t], sq);
    }
}

// ---- bn2 + output linear + bn3 stats (MFMA) ----
template <typename T>
__global__ __launch_bounds__(256) void k_outl(
    const float* __restrict__ wsW, const unsigned short* __restrict__ wsB,
    T* __restrict__ Y, const float* __restrict__ acc2, float* __restrict__ acc3)
{
    __shared__ __align__(16) unsigned short sxb[32][136];
    __shared__ float syf[32][132];
    __shared__ float nsc[C], nsh[C];
    int t = threadIdx.x;
    int row0 = blockIdx.x * 32;
    if (t < C) {
        float m = acc2[t] * (1.0f/NPTS);
        float v = acc2[C+t] * (1.0f/NPTS) - m*m;
        float rs = rsqrtf(v + EPS);
        float sc = rs * wsW[OFF_N2G + t];
        nsc[t] = sc;
        nsh[t] = wsW[OFF_N2B + t] - m * sc;
    }
    __syncthreads();
    for (int i = t; i < 32 * C; i += 256) {
        int c = i & 127;
        sxb[i>>7][c] = f2bf(ldE(Y, (long)row0 * C + i) * nsc[c] + nsh[c]);
    }
    __syncthreads();
    int lane = t & 63, w = t >> 6;
    int col = lane & 15, quad = lane >> 4;
    for (int tid = w; tid < 16; tid += 4) {
        int mt = tid & 1, nt = tid >> 1, n0 = nt * 16;
        f32x4 acc = {0.f, 0.f, 0.f, 0.f};
        const unsigned short* aB = &sxb[mt*16][0];
        const unsigned short* bB = wsB + B_OUTL + n0 * C;
        #pragma unroll
        for (int kt = 0; kt < 4; ++kt) {
            bfrag8 a = ldfrag(aB, 136, lane, kt*32);
            bfrag8 b = ldfrag(bB, C, lane, kt*32);
            acc = __builtin_amdgcn_mfma_f32_16x16x32_bf16(a, b, acc, 0, 0, 0);
        }
        #pragma unroll
        for (int r = 0; r < 4; ++r) {
            int m = mt*16 + quad*4 + r;
            int n = n0 + col;
            syf[m][n] = acc[r] + wsW[OFF_OUTL_B + n];
        }
    }
    __syncthreads();
    for (int i = t; i < 32 * CO; i += 256)
        stE(Y, (long)row0 * CO + i, syf[i>>7][i&127]);
    if (t < CO) {
        float s = 0.f, sq = 0.f;
        for (int r = 0; r < 32; ++r) { float v = syf[r][t]; s += v; sq += v*v; }
        atomicAdd(&acc3[t], s);
        atomicAdd(&acc3[CO+t], sq);
    }
}

// ---- final BN + relu -> output ----
template <typename T>
__global__ __launch_bounds__(256) void k_final(
    const float* __restrict__ wsW, const T* __restrict__ Y,
    const float* __restrict__ acc3, const int* __restrict__ flagp,
    void* __restrict__ out)
{
    long i = (long)blockIdx.x * 256 + threadIdx.x;
    int c = (int)(i & (CO-1));
    float m = acc3[c] * (1.0f/NPTS);
    float v = acc3[CO+c] * (1.0f/NPTS) - m*m;
    float rs = rsqrtf(v + EPS);
    float y = (ldE(Y, i) - m) * rs * wsW[OFF_BOG + c] + wsW[OFF_BOB + c];
    y = fmaxf(y, 0.f);
    if (*flagp) ((unsigned short*)out)[i] = f2bf(y);
    else        ((float*)out)[i] = y;
}

extern "C" void kernel_launch(void* const* d_in, const int* in_sizes, int n_in,
                              void* d_out, int out_size, void* d_ws, size_t ws_size,
                              hipStream_t stream)
{
    char* base = (char*)d_ws;
    float* wsW = (float*)base;
    float* acc1 = wsW + WTOTAL;
    float* acc2 = acc1 + 256;
    float* acc3 = acc2 + 256;
    int* flagp = (int*)(wsW + WTOTAL + 768);
    float* coords = wsW + WTOTAL + 776;
    unsigned short* wsB = (unsigned short*)(base + OFF_WB_BYTES);

    const void* featv = d_in[0];
    const int* indices = (const int*)d_in[1];
    const int* key_idx = (const int*)d_in[2];

    hipMemsetAsync(acc1, 0, 768 * sizeof(float), stream);
    k_detect<<<1, 256, 0, stream>>>((const unsigned short*)d_in[0], flagp);

    static const int cnt[20] = {49152,384,16384,128,384,128,384,128,128,128,
                                128,128,65536,512,65536,128,16384,128,128,128};
    static const int bofs[20] = {B_INPROJ,-1,B_OUTW,-1,-1,-1,-1,-1,-1,-1,
                                 -1,-1,B_LIN1,-1,B_LIN2,-1,B_OUTL,-1,-1,-1};
    WTab tab;
    int off = 0;
    for (int j = 0; j < 20; ++j) {
        tab.src[j] = d_in[3 + j];
        tab.beg[j] = off;
        tab.end[j] = off + cnt[j];
        tab.bo[j] = bofs[j];
        off += cnt[j];
    }
    k_cvt_weights<<<WTOTAL/256, 256, 0, stream>>>(tab, wsW, wsB, flagp);
    k_mkmat<<<128, 256, 0, stream>>>(wsW, wsB);

    size_t bigN = (size_t)NPTS * C;
    bool f32mode = (ws_size >= OFF_BIG_BYTES + QK_BYTES + bigN * 4);

    unsigned short* Qk = (unsigned short*)(base + OFF_BIG_BYTES);

    k_proj<<<NPTS/32, 256, 0, stream>>>(wsW, wsB, featv, flagp, indices, coords, Qk);
    k_attn<<<NPTS, 64, 0, stream>>>(wsW, wsB, coords, key_idx, featv, flagp, Qk);

    if (f32mode) {
        float* Y = (float*)(base + OFF_BIG_BYTES + QK_BYTES);
        k_outproj<float><<<NPTS/32, 256, 0, stream>>>(wsW, wsB, featv, flagp, Qk, Y, acc1);
        k_ffn<float><<<NPTS/32, 256, 0, stream>>>(wsW, wsB, Y, acc1, acc2);
        k_outl<float><<<NPTS/32, 256, 0, stream>>>(wsW, wsB, Y, acc2, acc3);
        k_final<float><<<(NPTS*CO)/256, 256, 0, stream>>>(wsW, Y, acc3, flagp, d_out);
    } else {
        unsigned short* Y = (unsigned short*)(base + OFF_BIG_BYTES + QK_BYTES);
        k_outproj<unsigned short><<<NPTS/32, 256, 0, stream>>>(wsW, wsB, featv, flagp, Qk, Y, acc1);
        k_ffn<unsigned short><<<NPTS/32, 256, 0, stream>>>(wsW, wsB, Y, acc1, acc2);
        k_outl<unsigned short><<<NPTS/32, 256, 0, stream>>>(wsW, wsB, Y, acc2, acc3);
        k_final<unsigned short><<<(NPTS*CO)/256, 256, 0, stream>>>(wsW, Y, acc3, flagp, d_out);
    }
}

// Round 14
// 686.310 us; speedup vs baseline: 1.3288x; 1.0551x over previous
//
#include <hip/hip_runtime.h>

#define NPTS 60000
#define C 128
#define K 32
#define FF 512
#define CO 128
#define H 8
#define DH 16
#define EPS 1e-5f

// ---- fp32 weight layout (float elements) ----
constexpr int OFF_INPROJ_W = 0;          // 384*128
constexpr int OFF_INPROJ_B = 49152;      // 384
constexpr int OFF_OUT_W    = 49536;      // 16384
constexpr int OFF_OUT_B    = 65920;      // 128
constexpr int OFF_QPOS_W   = 66048;      // 384
constexpr int OFF_QPOS_B   = 66432;      // 128
constexpr int OFF_KPOS_W   = 66560;      // 384
constexpr int OFF_KPOS_B   = 66944;      // 128
constexpr int OFF_N1G      = 67072;
constexpr int OFF_N1B      = 67200;
constexpr int OFF_N2G      = 67328;
constexpr int OFF_N2B      = 67456;
constexpr int OFF_LIN1_W   = 67584;      // 65536
constexpr int OFF_LIN1_B   = 133120;     // 512
constexpr int OFF_LIN2_W   = 133632;     // 65536
constexpr int OFF_LIN2_B   = 199168;     // 128
constexpr int OFF_OUTL_W   = 199296;     // 16384
constexpr int OFF_OUTL_B   = 215680;     // 128
constexpr int OFF_BOG      = 215808;
constexpr int OFF_BOB      = 215936;
constexpr int WTOTAL       = 216064;

// ---- bf16 weight copies (ushort elements within wsB) ----
constexpr int B_INPROJ = 0;        // 384x128
constexpr int B_OUTW   = 49152;    // 128x128 (layout keep)
constexpr int B_LIN1   = 65536;    // 512x128
constexpr int B_LIN2   = 131072;   // 128x512
constexpr int B_OUTL   = 196608;   // 128x128
constexpr int B_WKT    = 212992;   // 128x128
constexpr int B_KPW4   = 229376;   // 128 x float4 (fp32, 2048 B)
constexpr int B_M      = 230400;   // 128x1024 bf16 fused (outw ⊗ blockdiag wv)
constexpr int B_OB2    = 361472;   // 128 fp32: out_b + outw@bv
constexpr size_t OFF_WB_BYTES  = 1587456;
constexpr size_t OFF_BIG_BYTES = 2310912;
constexpr size_t QK_BYTES = (size_t)NPTS * 1024 * 2;   // qkt rows; reused as z rows

typedef __attribute__((ext_vector_type(8))) short bfrag8;
typedef __attribute__((ext_vector_type(4))) float f32x4;

__device__ __forceinline__ float bf2f(unsigned short s) {
    return __uint_as_float(((unsigned)s) << 16);
}
__device__ __forceinline__ unsigned short f2bf(float f) {
    unsigned u = __float_as_uint(f);
    u += 0x7fffu + ((u >> 16) & 1u);
    return (unsigned short)(u >> 16);
}
__device__ __forceinline__ float ldE(const float* p, long i) { return p[i]; }
__device__ __forceinline__ float ldE(const unsigned short* p, long i) { return bf2f(p[i]); }
__device__ __forceinline__ void stE(float* p, long i, float v) { p[i] = v; }
__device__ __forceinline__ void stE(unsigned short* p, long i, float v) { p[i] = f2bf(v); }
__device__ __forceinline__ float ldF(const void* p, long i, int bf) {
    return bf ? bf2f(((const unsigned short*)p)[i]) : ((const float*)p)[i];
}
__device__ __forceinline__ bfrag8 ldfrag(const unsigned short* base, int stride, int lane, int k0) {
    return *(const bfrag8*)(base + (lane & 15) * stride + k0 + ((lane >> 4) << 3));
}

// ---- dtype probe ----
__global__ __launch_bounds__(256) void k_detect(const unsigned short* __restrict__ f,
                                                int* __restrict__ flag) {
    __shared__ int cnt_s;
    if (threadIdx.x == 0) cnt_s = 0;
    __syncthreads();
    int sane = 0;
    for (int j = 0; j < 16; ++j) {
        unsigned short u = f[threadIdx.x * 16 + j];
        int e = (u >> 7) & 255;
        sane += (u == 0 || (e >= 100 && e <= 142)) ? 1 : 0;
    }
    atomicAdd(&cnt_s, sane);
    __syncthreads();
    if (threadIdx.x == 0) *flag = (cnt_s >= 3686) ? 1 : 0;
}

struct WTab {
    const void* src[20];
    int beg[20];
    int end[20];
    int bo[20];
};

__global__ __launch_bounds__(256) void k_cvt_weights(WTab tab, float* __restrict__ ws,
                                                     unsigned short* __restrict__ wsB,
                                                     const int* __restrict__ flagp) {
    int bf = *flagp;
    int gid = blockIdx.x * 256 + threadIdx.x;
    #pragma unroll
    for (int j = 0; j < 20; ++j) {
        if (gid >= tab.beg[j] && gid < tab.end[j]) {
            int off = gid - tab.beg[j];
            float v;
            unsigned short raw;
            if (bf) { raw = ((const unsigned short*)tab.src[j])[off]; v = bf2f(raw); }
            else    { v = ((const float*)tab.src[j])[off]; raw = f2bf(v); }
            ws[gid] = v;
            if (tab.bo[j] >= 0) wsB[tab.bo[j] + off] = raw;
            if (j == 0 && off >= 16384 && off < 32768) {
                int r = (off >> 7) - 128;
                int c = off & 127;
                wsB[B_WKT + c * C + r] = raw;
            }
            if (j == 6) {
                int c = off / 3, comp = off - 3 * c;
                ((float*)(wsB + B_KPW4))[c * 4 + comp] = v;
            }
            if (j == 7) {
                ((float*)(wsB + B_KPW4))[off * 4 + 3] = v;
            }
        }
    }
}

// ---- precompute M[j][h*128+c'] ; ob2 ----
__global__ __launch_bounds__(256) void k_mkmat(const float* __restrict__ wsW,
                                               unsigned short* __restrict__ wsBmut) {
    int j = blockIdx.x;
    int t = threadIdx.x;
    const float* outw = wsW + OFF_OUT_W + j * C;
    #pragma unroll
    for (int i = 0; i < 4; ++i) {
        int idx = t + i * 256;
        int h = idx >> 7, cp = idx & 127;
        float s = 0.f;
        const float* wvh = wsW + OFF_INPROJ_W + (256 + h * 16) * C + cp;
        const float* owh = outw + h * 16;
        #pragma unroll
        for (int d = 0; d < 16; ++d)
            s += owh[d] * wvh[d * C];
        wsBmut[B_M + j * 1024 + idx] = f2bf(s);
    }
    if (t == 0) {
        float s = wsW[OFF_OUT_B + j];
        const float* bv = wsW + OFF_INPROJ_B + 256;
        for (int c = 0; c < C; ++c) s += outw[c] * bv[c];
        ((float*)(wsBmut + B_OB2))[j] = s;
    }
}

// ---- fused coords + qpos + Q projection + per-head qkt precompute ----
__global__ __launch_bounds__(256) void k_proj(
    const float* __restrict__ wsW, const unsigned short* __restrict__ wsB,
    const void* __restrict__ featv, const int* __restrict__ flagp,
    const int* __restrict__ indices, float* __restrict__ coords,
    unsigned short* __restrict__ Qk)
{
    __shared__ __align__(16) unsigned short sqb[32][136];
    __shared__ __align__(16) unsigned short sqh[32][136];
    __shared__ __align__(16) unsigned short sqk[2][32][136];
    __shared__ float scd[32][4];
    int t = threadIdx.x;
    int row0 = blockIdx.x * 32;
    const int bf = *flagp;
    if (t < 96) {
        int r = t / 3, j = t - 3 * r;
        int n = row0 + r;
        int srci = (j == 0) ? 3 : (j == 1 ? 2 : 1);
        float vs = (j == 2) ? 0.2f : 0.1f;
        float mn = (j == 2) ? -3.0f : -40.0f;
        float v = ((float)indices[n * 4 + srci] + 0.5f) * vs + mn;
        scd[r][j] = v;
        coords[n * 3 + j] = v;
    }
    __syncthreads();
    const float* qpw = wsW + OFF_QPOS_W;
    const float* qpb = wsW + OFF_QPOS_B;
    for (int i = t; i < 32 * C; i += 256) {
        int r = i >> 7, c = i & 127;
        float x = ldF(featv, (long)row0 * C + i, bf);
        float a = qpb[c] + scd[r][0]*qpw[c*3] + scd[r][1]*qpw[c*3+1] + scd[r][2]*qpw[c*3+2];
        sqb[r][c] = f2bf(x + fmaxf(a, 0.0f));
    }
    __syncthreads();
    int lane = t & 63, w = t >> 6;
    int col = lane & 15, quad = lane >> 4;
    for (int tid = w; tid < 16; tid += 4) {
        int mt = tid & 1, nt = tid >> 1, n0 = nt * 16;
        f32x4 acc = {0.f, 0.f, 0.f, 0.f};
        const unsigned short* aB = &sqb[mt*16][0];
        const unsigned short* bB = wsB + B_INPROJ + n0 * C;
        #pragma unroll
        for (int kt = 0; kt < 4; ++kt) {
            bfrag8 a = ldfrag(aB, 136, lane, kt*32);
            bfrag8 b = ldfrag(bB, C, lane, kt*32);
            acc = __builtin_amdgcn_mfma_f32_16x16x32_bf16(a, b, acc, 0, 0, 0);
        }
        #pragma unroll
        for (int r = 0; r < 4; ++r) {
            int n = n0 + col;
            sqh[mt*16 + quad*4 + r][n] = f2bf(acc[r] + wsW[OFF_INPROJ_B + n]);
        }
    }
    __syncthreads();
    const unsigned short* wkT = wsB + B_WKT;
    bfrag8 zf = {0,0,0,0,0,0,0,0};
    for (int h = 0; h < 8; ++h) {
        for (int tid = w; tid < 16; tid += 4) {
            int mt = tid & 1, nt = tid >> 1, n0 = nt * 16;
            bfrag8 a = zf, b = zf;
            if (quad < 2) {
                a = *(const bfrag8*)(&sqh[mt*16 + col][h*16 + quad*8]);
                b = *(const bfrag8*)(wkT + (n0 + col) * C + h*16 + quad*8);
            }
            f32x4 acc = {0.f, 0.f, 0.f, 0.f};
            acc = __builtin_amdgcn_mfma_f32_16x16x32_bf16(a, b, acc, 0, 0, 0);
            #pragma unroll
            for (int r = 0; r < 4; ++r)
                sqk[h & 1][mt*16 + quad*4 + r][n0 + col] = f2bf(acc[r]);
        }
        __syncthreads();
        for (int i = t; i < 2048; i += 256) {
            int r = i >> 6, cp = i & 63;
            unsigned v = *(const unsigned*)&sqk[h & 1][r][2 * cp];
            ((unsigned*)Qk)[(long)(row0 + r) * 512 + h * 64 + cp] = v;
        }
    }
}

// ---- attention: ONE wave per block; outputs z rows (in-place over Qk) ----
__global__ __launch_bounds__(64) void k_attn(
    const float* __restrict__ wsW, const unsigned short* __restrict__ wsB,
    const float* __restrict__ coords, const int* __restrict__ key_idx,
    const void* __restrict__ featv, const int* __restrict__ flagp,
    unsigned short* __restrict__ Qk)
{
    __shared__ __align__(16) unsigned short P[32][136];
    __shared__ __align__(16) unsigned short QZ[8][136];
    __shared__ __align__(16) float SC[8][36];
    __shared__ __align__(16) float REL[32][4];
    __shared__ __align__(16) int   GS[32];

    int l = threadIdx.x;
    int n = blockIdx.x;
    int col = l & 15, quad = l >> 4;
    int c0 = 2 * l;
    const int bf = *flagp;

    const float* kpwp = wsW + OFF_KPOS_W;
    float kw00 = kpwp[c0*3],   kw01 = kpwp[c0*3+1], kw02 = kpwp[c0*3+2];
    float kw10 = kpwp[c0*3+3], kw11 = kpwp[c0*3+4], kw12 = kpwp[c0*3+5];
    float kb0 = wsW[OFF_KPOS_B + c0], kb1 = wsW[OFF_KPOS_B + c0 + 1];

    if (l < 32) GS[l] = key_idx[n * K + l];
    float cenx = coords[n*3+0], ceny = coords[n*3+1], cenz = coords[n*3+2];
    bfrag8 ak[4];
    {
        const unsigned short* qkrow = Qk + (long)n * 1024 + (col & 7) * 128;
        #pragma unroll
        for (int ks = 0; ks < 4; ++ks)
            ak[ks] = *(const bfrag8*)(qkrow + ks * 32 + quad * 8);
    }
    if (l < 32) {
        int gc = max(GS[l], 0);
        REL[l][0] = coords[gc*3+0] - cenx;
        REL[l][1] = coords[gc*3+1] - ceny;
        REL[l][2] = coords[gc*3+2] - cenz;
        REL[l][3] = 0.f;
    }
    __syncthreads();

    if (bf) {
        const unsigned* xb = (const unsigned*)featv;
        #pragma unroll 8
        for (int k = 0; k < K; ++k) {
            int gc = max(GS[k], 0);
            unsigned xv = xb[(long)gc * 64 + l];
            float4 rr = *(const float4*)&REL[k][0];
            float p0 = bf2f((unsigned short)xv)
                     + fmaxf(kb0 + rr.x*kw00 + rr.y*kw01 + rr.z*kw02, 0.f);
            float p1 = bf2f((unsigned short)(xv >> 16))
                     + fmaxf(kb1 + rr.x*kw10 + rr.y*kw11 + rr.z*kw12, 0.f);
            *(unsigned*)&P[k][c0] = (unsigned)f2bf(p0) | ((unsigned)f2bf(p1) << 16);
        }
    } else {
        const float2* xf = (const float2*)featv;
        #pragma unroll 8
        for (int k = 0; k < K; ++k) {
            int gc = max(GS[k], 0);
            float2 xv = xf[(long)gc * 64 + l];
            float4 rr = *(const float4*)&REL[k][0];
            float p0 = xv.x + fmaxf(kb0 + rr.x*kw00 + rr.y*kw01 + rr.z*kw02, 0.f);
            float p1 = xv.y + fmaxf(kb1 + rr.x*kw10 + rr.y*kw11 + rr.z*kw12, 0.f);
            *(unsigned*)&P[k][c0] = (unsigned)f2bf(p0) | ((unsigned)f2bf(p1) << 16);
        }
    }
    __syncthreads();

    #pragma unroll
    for (int nt = 0; nt < 2; ++nt) {
        int g = GS[nt * 16 + col];
        f32x4 acc = {0.f, 0.f, 0.f, 0.f};
        #pragma unroll
        for (int ks = 0; ks < 4; ++ks) {
            bfrag8 bp = *(const bfrag8*)(&P[nt * 16 + col][0] + ks * 32 + quad * 8);
            acc = __builtin_amdgcn_mfma_f32_16x16x32_bf16(ak[ks], bp, acc, 0, 0, 0);
        }
        if (quad < 2) {
            #pragma unroll
            for (int r = 0; r < 4; ++r) {
                int h = quad * 4 + r, k = nt * 16 + col;
                SC[h][k] = (g < 0) ? -1e30f : acc[r] * 0.25f;
            }
        }
    }
    __syncthreads();

    {
        int h = l >> 3, sub = l & 7;
        float v0 = SC[h][sub],      v1 = SC[h][sub + 8];
        float v2 = SC[h][sub + 16], v3 = SC[h][sub + 24];
        float m = fmaxf(fmaxf(v0, v1), fmaxf(v2, v3));
        m = fmaxf(m, __shfl_xor(m, 1));
        m = fmaxf(m, __shfl_xor(m, 2));
        m = fmaxf(m, __shfl_xor(m, 4));
        float e0 = __expf(v0 - m), e1 = __expf(v1 - m), e2 = __expf(v2 - m), e3 = __expf(v3 - m);
        float s = e0 + e1 + e2 + e3;
        s += __shfl_xor(s, 1);
        s += __shfl_xor(s, 2);
        s += __shfl_xor(s, 4);
        float inv = 1.0f / s;
        SC[h][sub]      = e0 * inv;
        SC[h][sub + 8]  = e1 * inv;
        SC[h][sub + 16] = e2 * inv;
        SC[h][sub + 24] = e3 * inv;
    }
    __syncthreads();

    {
        union { bfrag8 f; unsigned short u[8]; } at8;
        #pragma unroll
        for (int j = 0; j < 8; ++j)
            at8.u[j] = f2bf(SC[col & 7][quad * 8 + j]);
        #pragma unroll
        for (int nt = 0; nt < 8; ++nt) {
            union { bfrag8 f; unsigned short u[8]; } bt;
            #pragma unroll
            for (int j = 0; j < 8; ++j)
                bt.u[j] = P[quad * 8 + j][nt * 16 + col];
            f32x4 d = {0.f, 0.f, 0.f, 0.f};
            d = __builtin_amdgcn_mfma_f32_16x16x32_bf16(at8.f, bt.f, d, 0, 0, 0);
            if (quad < 2) {
                #pragma unroll
                for (int r = 0; r < 4; ++r)
                    QZ[quad * 4 + r][nt * 16 + col] = f2bf(d[r]);
            }
        }
    }
    __syncthreads();

    {
        unsigned* zout = (unsigned*)(Qk + (long)n * 1024);
        #pragma unroll
        for (int j = 0; j < 8; ++j) {
            int idx = l + j * 64;
            zout[idx] = *(const unsigned*)&QZ[idx >> 6][(idx & 63) * 2];
        }
    }
}

// ---- out-proj from z: y1 = feat + z @ M^T + ob2 ; bn1 stats ----
template <typename T>
__global__ __launch_bounds__(256) void k_outproj(
    const float* __restrict__ wsW, const unsigned short* __restrict__ wsB,
    const void* __restrict__ featv, const int* __restrict__ flagp,
    const unsigned short* __restrict__ Z, T* __restrict__ Y, float* __restrict__ acc_s)
{
    __shared__ float syf[32][132];
    int t = threadIdx.x;
    int row0 = blockIdx.x * 32;
    const int bf = *flagp;
    int lane = t & 63, w = t >> 6;
    int col = lane & 15, quad = lane >> 4;
    const unsigned short* M = wsB + B_M;
    const float* ob2 = (const float*)(wsB + B_OB2);
    int mt = w & 1, ntb = w >> 1;
    f32x4 acc[4] = {{0,0,0,0},{0,0,0,0},{0,0,0,0},{0,0,0,0}};
    const unsigned short* zrow = Z + (long)(row0 + mt*16 + col) * 1024 + quad * 8;
    #pragma unroll
    for (int ktc = 0; ktc < 4; ++ktc) {
        bfrag8 a[8];
        #pragma unroll
        for (int j = 0; j < 8; ++j)
            a[j] = *(const bfrag8*)(zrow + (ktc * 8 + j) * 32);
        #pragma unroll
        for (int i = 0; i < 4; ++i) {
            int n0 = (ntb + 2 * i) * 16;
            const unsigned short* mrow = M + (n0 + col) * 1024 + quad * 8;
            #pragma unroll
            for (int j = 0; j < 8; ++j) {
                bfrag8 b = *(const bfrag8*)(mrow + (ktc * 8 + j) * 32);
                acc[i] = __builtin_amdgcn_mfma_f32_16x16x32_bf16(a[j], b, acc[i], 0, 0, 0);
            }
        }
    }
    #pragma unroll
    for (int i = 0; i < 4; ++i) {
        int n0 = (ntb + 2 * i) * 16;
        #pragma unroll
        for (int r = 0; r < 4; ++r) {
            int m = mt*16 + quad*4 + r;
            int n = n0 + col;
            syf[m][n] = acc[i][r] + ob2[n] + ldF(featv, (long)(row0+m)*C + n, bf);
        }
    }
    __syncthreads();
    for (int i = t; i < 32 * C; i += 256)
        stE(Y, (long)row0 * C + i, syf[i>>7][i&127]);
    if (t < C) {
        float s = 0.f, sq = 0.f;
        for (int r = 0; r < 32; ++r) { float v = syf[r][t]; s += v; sq += v*v; }
        atomicAdd(&acc_s[t], s);
        atomicAdd(&acc_s[C + t], sq);
    }
}

// ---- bn1 + FFN + residual + bn2 stats (MFMA, FF split in 2 halves, 26.6 KB LDS) ----
template <typename T>
__global__ __launch_bounds__(256) void k_ffn(
    const float* __restrict__ wsW, const unsigned short* __restrict__ wsB,
    T* __restrict__ Y, const float* __restrict__ acc1, float* __restrict__ acc2)
{
    __shared__ __align__(16) unsigned short sxb[32][136];
    __shared__ __align__(16) unsigned short sh[32][264];   // one FF half
    __shared__ float nsc[C], nsh[C];
    float (*syf)[132] = (float(*)[132])sh;                 // aliased after last half
    int t = threadIdx.x;
    int row0 = blockIdx.x * 32;
    if (t < C) {
        float m = acc1[t] * (1.0f/NPTS);
        float v = acc1[C+t] * (1.0f/NPTS) - m*m;
        float rs = rsqrtf(v + EPS);
        float sc = rs * wsW[OFF_N1G + t];
        nsc[t] = sc;
        nsh[t] = wsW[OFF_N1B + t] - m * sc;
    }
    __syncthreads();
    for (int i = t; i < 32 * C; i += 256) {
        int c = i & 127;
        sxb[i>>7][c] = f2bf(ldE(Y, (long)row0 * C + i) * nsc[c] + nsh[c]);
    }
    __syncthreads();
    int lane = t & 63, w = t >> 6;
    int col = lane & 15, quad = lane >> 4;
    int mtw = w & 1, ntb = w >> 1;
    f32x4 accT[4] = {{0,0,0,0},{0,0,0,0},{0,0,0,0},{0,0,0,0}};
    #pragma unroll
    for (int half = 0; half < 2; ++half) {
        // GEMM1: 32 x [C] @ lin1[half*256 .. +256]^T -> sh (relu, bf16)
        for (int tid = w; tid < 32; tid += 4) {
            int mt = tid & 1, nt = tid >> 1, n0 = nt * 16;
            f32x4 acc = {0.f, 0.f, 0.f, 0.f};
            const unsigned short* aB = &sxb[mt*16][0];
            const unsigned short* bB = wsB + B_LIN1 + (half * 256 + n0) * C;
            #pragma unroll
            for (int kt = 0; kt < 4; ++kt) {
                bfrag8 a = ldfrag(aB, 136, lane, kt*32);
                bfrag8 b = ldfrag(bB, C, lane, kt*32);
                acc = __builtin_amdgcn_mfma_f32_16x16x32_bf16(a, b, acc, 0, 0, 0);
            }
            #pragma unroll
            for (int r = 0; r < 4; ++r) {
                int m = mt*16 + quad*4 + r;
                int nf = half * 256 + n0 + col;
                sh[m][n0 + col] = f2bf(fmaxf(acc[r] + wsW[OFF_LIN1_B + nf], 0.f));
            }
        }
        __syncthreads();
        // GEMM2 partial-K accumulate over this half
        #pragma unroll
        for (int i = 0; i < 4; ++i) {
            int mt = mtw, n0 = (ntb + 2 * i) * 16;
            const unsigned short* aB = &sh[mt*16][0];
            const unsigned short* bB = wsB + B_LIN2 + (n0 + col) * FF + half * 256;
            #pragma unroll
            for (int kt = 0; kt < 8; ++kt) {
                bfrag8 a = ldfrag(aB, 264, lane, kt*32);
                bfrag8 b = *(const bfrag8*)(bB + kt * 32 + quad * 8);
                accT[i] = __builtin_amdgcn_mfma_f32_16x16x32_bf16(a, b, accT[i], 0, 0, 0);
            }
        }
        __syncthreads();
    }
    #pragma unroll
    for (int i = 0; i < 4; ++i) {
        int n0 = (ntb + 2 * i) * 16;
        #pragma unroll
        for (int r = 0; r < 4; ++r) {
            int m = mtw*16 + quad*4 + r;
            int n = n0 + col;
            syf[m][n] = accT[i][r] + wsW[OFF_LIN2_B + n] + bf2f(sxb[m][n]);
        }
    }
    __syncthreads();
    for (int i = t; i < 32 * C; i += 256)
        stE(Y, (long)row0 * C + i, syf[i>>7][i&127]);
    if (t < C) {
        float s = 0.f, sq = 0.f;
        for (int r = 0; r < 32; ++r) { float v = syf[r][t]; s += v; sq += v*v; }
        atomicAdd(&acc2[t], s);
        atomicAdd(&acc2[C+t], sq);
    }
}

// ---- bn2 + output linear + bn3 stats (MFMA) ----
template <typename T>
__global__ __launch_bounds__(256) void k_outl(
    const float* __restrict__ wsW, const unsigned short* __restrict__ wsB,
    T* __restrict__ Y, const float* __restrict__ acc2, float* __restrict__ acc3)
{
    __shared__ __align__(16) unsigned short sxb[32][136];
    __shared__ float syf[32][132];
    __shared__ float nsc[C], nsh[C];
    int t = threadIdx.x;
    int row0 = blockIdx.x * 32;
    if (t < C) {
        float m = acc2[t] * (1.0f/NPTS);
        float v = acc2[C+t] * (1.0f/NPTS) - m*m;
        float rs = rsqrtf(v + EPS);
        float sc = rs * wsW[OFF_N2G + t];
        nsc[t] = sc;
        nsh[t] = wsW[OFF_N2B + t] - m * sc;
    }
    __syncthreads();
    for (int i = t; i < 32 * C; i += 256) {
        int c = i & 127;
        sxb[i>>7][c] = f2bf(ldE(Y, (long)row0 * C + i) * nsc[c] + nsh[c]);
    }
    __syncthreads();
    int lane = t & 63, w = t >> 6;
    int col = lane & 15, quad = lane >> 4;
    for (int tid = w; tid < 16; tid += 4) {
        int mt = tid & 1, nt = tid >> 1, n0 = nt * 16;
        f32x4 acc = {0.f, 0.f, 0.f, 0.f};
        const unsigned short* aB = &sxb[mt*16][0];
        const unsigned short* bB = wsB + B_OUTL + n0 * C;
        #pragma unroll
        for (int kt = 0; kt < 4; ++kt) {
            bfrag8 a = ldfrag(aB, 136, lane, kt*32);
            bfrag8 b = ldfrag(bB, C, lane, kt*32);
            acc = __builtin_amdgcn_mfma_f32_16x16x32_bf16(a, b, acc, 0, 0, 0);
        }
        #pragma unroll
        for (int r = 0; r < 4; ++r) {
            int m = mt*16 + quad*4 + r;
            int n = n0 + col;
            syf[m][n] = acc[r] + wsW[OFF_OUTL_B + n];
        }
    }
    __syncthreads();
    for (int i = t; i < 32 * CO; i += 256)
        stE(Y, (long)row0 * CO + i, syf[i>>7][i&127]);
    if (t < CO) {
        float s = 0.f, sq = 0.f;
        for (int r = 0; r < 32; ++r) { float v = syf[r][t]; s += v; sq += v*v; }
        atomicAdd(&acc3[t], s);
        atomicAdd(&acc3[CO+t], sq);
    }
}

// ---- final BN + relu -> output ----
template <typename T>
__global__ __launch_bounds__(256) void k_final(
    const float* __restrict__ wsW, const T* __restrict__ Y,
    const float* __restrict__ acc3, const int* __restrict__ flagp,
    void* __restrict__ out)
{
    long i = (long)blockIdx.x * 256 + threadIdx.x;
    int c = (int)(i & (CO-1));
    float m = acc3[c] * (1.0f/NPTS);
    float v = acc3[CO+c] * (1.0f/NPTS) - m*m;
    float rs = rsqrtf(v + EPS);
    float y = (ldE(Y, i) - m) * rs * wsW[OFF_BOG + c] + wsW[OFF_BOB + c];
    y = fmaxf(y, 0.f);
    if (*flagp) ((unsigned short*)out)[i] = f2bf(y);
    else        ((float*)out)[i] = y;
}

extern "C" void kernel_launch(void* const* d_in, const int* in_sizes, int n_in,
                              void* d_out, int out_size, void* d_ws, size_t ws_size,
                              hipStream_t stream)
{
    char* base = (char*)d_ws;
    float* wsW = (float*)base;
    float* acc1 = wsW + WTOTAL;
    float* acc2 = acc1 + 256;
    float* acc3 = acc2 + 256;
    int* flagp = (int*)(wsW + WTOTAL + 768);
    float* coords = wsW + WTOTAL + 776;
    unsigned short* wsB = (unsigned short*)(base + OFF_WB_BYTES);

    const void* featv = d_in[0];
    const int* indices = (const int*)d_in[1];
    const int* key_idx = (const int*)d_in[2];

    hipMemsetAsync(acc1, 0, 768 * sizeof(float), stream);
    k_detect<<<1, 256, 0, stream>>>((const unsigned short*)d_in[0], flagp);

    static const int cnt[20] = {49152,384,16384,128,384,128,384,128,128,128,
                                128,128,65536,512,65536,128,16384,128,128,128};
    static const int bofs[20] = {B_INPROJ,-1,B_OUTW,-1,-1,-1,-1,-1,-1,-1,
                                 -1,-1,B_LIN1,-1,B_LIN2,-1,B_OUTL,-1,-1,-1};
    WTab tab;
    int off = 0;
    for (int j = 0; j < 20; ++j) {
        tab.src[j] = d_in[3 + j];
        tab.beg[j] = off;
        tab.end[j] = off + cnt[j];
        tab.bo[j] = bofs[j];
        off += cnt[j];
    }
    k_cvt_weights<<<WTOTAL/256, 256, 0, stream>>>(tab, wsW, wsB, flagp);
    k_mkmat<<<128, 256, 0, stream>>>(wsW, wsB);

    size_t bigN = (size_t)NPTS * C;
    bool f32mode = (ws_size >= OFF_BIG_BYTES + QK_BYTES + bigN * 4);

    unsigned short* Qk = (unsigned short*)(base + OFF_BIG_BYTES);

    k_proj<<<NPTS/32, 256, 0, stream>>>(wsW, wsB, featv, flagp, indices, coords, Qk);
    k_attn<<<NPTS, 64, 0, stream>>>(wsW, wsB, coords, key_idx, featv, flagp, Qk);

    if (f32mode) {
        float* Y = (float*)(base + OFF_BIG_BYTES + QK_BYTES);
        k_outproj<float><<<NPTS/32, 256, 0, stream>>>(wsW, wsB, featv, flagp, Qk, Y, acc1);
        k_ffn<float><<<NPTS/32, 256, 0, stream>>>(wsW, wsB, Y, acc1, acc2);
        k_outl<float><<<NPTS/32, 256, 0, stream>>>(wsW, wsB, Y, acc2, acc3);
        k_final<float><<<(NPTS*CO)/256, 256, 0, stream>>>(wsW, Y, acc3, flagp, d_out);
    } else {
        unsigned short* Y = (unsigned short*)(base + OFF_BIG_BYTES + QK_BYTES);
        k_outproj<unsigned short><<<NPTS/32, 256, 0, stream>>>(wsW, wsB, featv, flagp, Qk, Y, acc1);
        k_ffn<unsigned short><<<NPTS/32, 256, 0, stream>>>(wsW, wsB, Y, acc1, acc2);
        k_outl<unsigned short><<<NPTS/32, 256, 0, stream>>>(wsW, wsB, Y, acc2, acc3);
        k_final<unsigned short><<<(NPTS*CO)/256, 256, 0, stream>>>(wsW, Y, acc3, flagp, d_out);
    }
}